// Round 2
// baseline (474.663 us; speedup 1.0000x reference)
//
#include <hip/hip_runtime.h>
#include <hip/hip_bf16.h>

#define B_   4
#define S_   2048
#define D_   1024
#define H_   16
#define DH_  64
#define M_   (B_ * S_)

typedef __attribute__((ext_vector_type(8))) short  bfrag8;   // 8 bf16 = 4 VGPRs
typedef __attribute__((ext_vector_type(4))) float  facc4;    // 4 fp32 accum
typedef unsigned short u16;
typedef unsigned long long u64;

__device__ __forceinline__ u16 f2bf(float f) {
    union { __hip_bfloat16 h; u16 u; } c;
    c.h = __float2bfloat16(f);
    return c.u;
}

// manual RNE fp32->bf16 (finite inputs only)
__device__ __forceinline__ u16 bfr(float f) {
    unsigned b = __float_as_uint(f);
    return (u16)((b + 0x7FFFu + ((b >> 16) & 1u)) >> 16);
}

// async global->LDS, 16B per lane; LDS dest must be wave-uniform base + lane*16
__device__ __forceinline__ void gl_lds16(const u16* g, u16* l) {
    __builtin_amdgcn_global_load_lds((const __attribute__((address_space(1))) void*)g,
                                     (__attribute__((address_space(3))) void*)l,
                                     16, 0, 0);
}

// ---------------------------------------------------------------------------
// fp32 -> bf16 elementwise convert (x)
// ---------------------------------------------------------------------------
__global__ __launch_bounds__(256) void cvt_x(const float* __restrict__ x,
                                             u16* __restrict__ o, int n) {
    int i = (blockIdx.x * 256 + threadIdx.x) * 4;
    if (i >= n) return;
    float4 v = *(const float4*)(x + i);
    ushort4 r;
    r.x = f2bf(v.x); r.y = f2bf(v.y); r.z = f2bf(v.z); r.w = f2bf(v.w);
    *(ushort4*)(o + i) = r;
}

// ---------------------------------------------------------------------------
// fp32 W[k][n] -> bf16 WT[n][k] transpose+convert, 32x32 LDS tiles.
// ---------------------------------------------------------------------------
__global__ __launch_bounds__(256) void cvt_wt(const float* __restrict__ w0, const float* __restrict__ w1,
                                              const float* __restrict__ w2, const float* __restrict__ w3,
                                              u16* __restrict__ o0, u16* __restrict__ o1,
                                              u16* __restrict__ o2, u16* __restrict__ o3) {
    const float* w; u16* o;
    switch (blockIdx.z) {
        case 0: w = w0; o = o0; break;
        case 1: w = w1; o = o1; break;
        case 2: w = w2; o = o2; break;
        default: w = w3; o = o3; break;
    }
    __shared__ u16 t[32][33];
    int kb = blockIdx.x * 32, nb = blockIdx.y * 32;
    int c = threadIdx.x & 31, r0 = threadIdx.x >> 5;
#pragma unroll
    for (int i = 0; i < 4; i++) {
        int r = r0 + 8 * i;
        t[r][c] = f2bf(w[(kb + r) * D_ + nb + c]);
    }
    __syncthreads();
#pragma unroll
    for (int i = 0; i < 4; i++) {
        int r = r0 + 8 * i;
        o[(nb + r) * D_ + kb + c] = t[c][r];
    }
}

// ---------------------------------------------------------------------------
// m97-style GEMM body: C[M,N] = (A[M,K] @ BT[N,K]^T + bias) * scale.
// 128x128 tile, BK=32, global_load_lds 16B staging, XOR chunk swizzle.
// ---------------------------------------------------------------------------
__device__ __forceinline__ void gemm_body(const u16* __restrict__ A,
                                          const u16* __restrict__ BT,
                                          const float* __restrict__ bias,
                                          void* __restrict__ Cout, int mode, float scale,
                                          u16* As, u16* Bs) {
    int tid = threadIdx.x;
    int nb = blockIdx.x * 128, mb = blockIdx.y * 128;
    int w = tid >> 6, lane = tid & 63, quad = lane >> 4, l16 = lane & 15;
    int wm = (w >> 1) * 64, wn = (w & 1) * 64;

    int c0 = tid, c1 = tid + 256;
    int row0 = c0 >> 2, row1 = c1 >> 2;
    int sw0 = (c0 & 3) ^ ((row0 >> 2) & 3);
    int sw1 = (c1 & 3) ^ ((row1 >> 2) & 3);
    const u16* Ag0 = A + (mb + row0) * D_ + sw0 * 8;
    const u16* Ag1 = A + (mb + row1) * D_ + sw1 * 8;
    const u16* Bg0 = BT + (nb + row0) * D_ + sw0 * 8;
    const u16* Bg1 = BT + (nb + row1) * D_ + sw1 * 8;
    u16* Al0 = As + c0 * 8; u16* Al1 = As + c1 * 8;
    u16* Bl0 = Bs + c0 * 8; u16* Bl1 = Bs + c1 * 8;

    int swr = (l16 >> 2) & 3;

    facc4 acc[4][4] = {};
    for (int kk = 0; kk < D_; kk += 32) {
        __syncthreads();
        gl_lds16(Ag0 + kk, Al0);
        gl_lds16(Ag1 + kk, Al1);
        gl_lds16(Bg0 + kk, Bl0);
        gl_lds16(Bg1 + kk, Bl1);
        __syncthreads();

        bfrag8 af[4], bf[4];
#pragma unroll
        for (int mt = 0; mt < 4; ++mt)
            af[mt] = *(const bfrag8*)(As + (wm + mt * 16 + l16) * 32 + ((quad ^ swr) << 3));
#pragma unroll
        for (int nt = 0; nt < 4; ++nt)
            bf[nt] = *(const bfrag8*)(Bs + (wn + nt * 16 + l16) * 32 + ((quad ^ swr) << 3));
#pragma unroll
        for (int mt = 0; mt < 4; ++mt)
#pragma unroll
            for (int nt = 0; nt < 4; ++nt)
                acc[mt][nt] = __builtin_amdgcn_mfma_f32_16x16x32_bf16(af[mt], bf[nt], acc[mt][nt], 0, 0, 0);
    }

#pragma unroll
    for (int mt = 0; mt < 4; ++mt) {
        int m_base = mb + wm + mt * 16 + quad * 4;
#pragma unroll
        for (int nt = 0; nt < 4; ++nt) {
            int n = nb + wn + nt * 16 + l16;
            float bv = bias[n];
            int h = n >> 6, dd = n & 63;
#pragma unroll
            for (int r = 0; r < 4; ++r) {
                int m = m_base + r;
                float v = (acc[mt][nt][r] + bv) * scale;
                int bi = m >> 11, s = m & (S_ - 1);
                if (mode == 0) {
                    ((u16*)Cout)[(((bi * H_ + h) * S_) + s) * DH_ + dd] = bfr(v);
                } else if (mode == 1) {
                    ((u16*)Cout)[(((bi * H_ + h) * DH_) + dd) * S_ + s] = bfr(v);
                } else {
                    ((float*)Cout)[(size_t)m * D_ + n] = v;
                }
            }
        }
    }
}

#define CE_Q 0.18033688011112042f   // log2(e)/sqrt(DH), folded into Q

__global__ __launch_bounds__(256) void gemm_qkv(const u16* __restrict__ A,
                                                const u16* __restrict__ WTq, const float* __restrict__ bq, u16* __restrict__ Qb,
                                                const u16* __restrict__ WTk, const float* __restrict__ bk, u16* __restrict__ Kb,
                                                const u16* __restrict__ WTv, const float* __restrict__ bv, u16* __restrict__ VTb) {
    __shared__ u16 As[128 * 32];
    __shared__ u16 Bs[128 * 32];
    switch (blockIdx.z) {
        case 0: gemm_body(A, WTq, bq, Qb, 0, CE_Q, As, Bs); break;   // Q pre-scaled
        case 1: gemm_body(A, WTk, bk, Kb, 0, 1.0f, As, Bs); break;
        default: gemm_body(A, WTv, bv, VTb, 1, 1.0f, As, Bs); break;
    }
}

__global__ __launch_bounds__(256) void gemm_o(const u16* __restrict__ A,
                                              const u16* __restrict__ WTo, const float* __restrict__ bo,
                                              float* __restrict__ out) {
    __shared__ u16 As[128 * 32];
    __shared__ u16 Bs[128 * 32];
    gemm_body(A, WTo, bo, out, 2, 1.0f, As, Bs);
}

// ---------------------------------------------------------------------------
// Flash attention, S^T/O^T formulation, fixed-base softmax, zero LDS,
// zero barriers.
// R1 restructure (occupancy was grid-bound at 21.7%, MfmaUtil 10.5%):
//  - qt-split: each wave handles ONE 16-row q-subtile of chunk pair (u,63-u)
//    -> 4096 perfectly-balanced 65-iter waves (was 2048), grid 1024 blocks
//    = 4/CU all co-resident -> 50% occupancy ceiling.
//  - XCD bh-affinity swizzle: all 16 blocks of one (b,h) land on one XCD
//    (blockId%8 round-robin) -> K/V (512KB/bh) stays L2-resident.
//  - launch_bounds(256,4) caps VGPR at 128 so 4 blocks/CU fit.
// T5 s_setprio around MFMA clusters kept (independent-wave regime, m191).
// ---------------------------------------------------------------------------
// exp2 + pack + lane-transpose (bpermute) + PV accumulate for one q-tile
__device__ __forceinline__ void soft_pv(const float* p, float& lp, facc4* oaccq,
                                        const bfrag8* vf, int a0, int a1, bool qlo) {
    float rs = 0.f;
    unsigned pk[4];
#pragma unroll
    for (int j = 0; j < 4; ++j) {
        float e0 = exp2f(p[2 * j]);
        float e1 = exp2f(p[2 * j + 1]);
        rs += e0; rs += e1;
        pk[j] = __builtin_amdgcn_perm(__float_as_uint(e1), __float_as_uint(e0), 0x07060302u);
    }
    lp += rs;                                   // per-lane partial; reduced once per chunk
    union { unsigned d[4]; bfrag8 v; } pb;
    {
        unsigned lo, hi;
        lo = __builtin_amdgcn_ds_bpermute(a0, (int)pk[0]);
        hi = __builtin_amdgcn_ds_bpermute(a0, (int)pk[2]);
        pb.d[0] = qlo ? lo : hi;
        lo = __builtin_amdgcn_ds_bpermute(a0, (int)pk[1]);
        hi = __builtin_amdgcn_ds_bpermute(a0, (int)pk[3]);
        pb.d[1] = qlo ? lo : hi;
        lo = __builtin_amdgcn_ds_bpermute(a1, (int)pk[0]);
        hi = __builtin_amdgcn_ds_bpermute(a1, (int)pk[2]);
        pb.d[2] = qlo ? lo : hi;
        lo = __builtin_amdgcn_ds_bpermute(a1, (int)pk[1]);
        hi = __builtin_amdgcn_ds_bpermute(a1, (int)pk[3]);
        pb.d[3] = qlo ? lo : hi;
    }
    __builtin_amdgcn_s_setprio(1);
#pragma unroll
    for (int dt = 0; dt < 4; ++dt)
        oaccq[dt] = __builtin_amdgcn_mfma_f32_16x16x32_bf16(vf[dt], pb.v, oaccq[dt], 0, 0, 0);
    __builtin_amdgcn_s_setprio(0);
}

__global__ __launch_bounds__(256, 4) void attn(const u16* __restrict__ Q,
                                               const u16* __restrict__ K,
                                               const u16* __restrict__ VT,
                                               const int* __restrict__ pm,
                                               u16* __restrict__ Aout) {
    int tid = threadIdx.x, w = tid >> 6, lane = tid & 63;
    int quad = lane >> 4, l16 = lane & 15;

    // XCD bh-affinity swizzle: lid -> (xcd, idx); all 16 blocks of one (b,h)
    // share lid%8 == xcd, so they land on one XCD's L2 (512KB K+V << 4MB).
    int lid = blockIdx.x + 16 * (blockIdx.y + 16 * blockIdx.z);  // [0,1024)
    int xcd = lid & 7, idx = lid >> 3;         // idx in [0,128)
    int bh  = xcd * 8 + (idx & 7);             // [0,64)
    int jgr = idx >> 3;                        // [0,16) chunk-pair group
    int b = bh >> 4, h = bh & 15;

    int v  = jgr * 4 + w;                      // [0,64) wave task
    int u  = v >> 1;                           // pair id [0,32)
    int qt = v & 1;                            // which 16-row q-subtile

    const u16* Qp = Q + (size_t)(b * H_ + h) * S_ * DH_;
    const u16* Kp = K + (size_t)(b * H_ + h) * S_ * DH_;
    const u16* Vp = VT + (size_t)(b * H_ + h) * DH_ * S_;
    const int* pmb = pm + b * S_;
    u16* Ao = Aout + (size_t)b * S_ * D_ + h * DH_;

    // bpermute byte-addresses for the P^T lane permute (loop-invariant)
    int a0 = ((((2 * quad) & 3) * 16 + l16) << 2);
    int a1 = ((((2 * quad + 1) & 3) * 16 + l16) << 2);
    bool qlo = quad < 2;

    for (int half = 0; half < 2; ++half) {
        int c = half ? 63 - u : u;              // chunk 0..63 (32 q-rows)
        int qw = c * 32 + qt * 16;              // this wave's 16 q-rows

        bfrag8 qf[2];
#pragma unroll
        for (int cc = 0; cc < 2; ++cc)
            qf[cc] = *(const bfrag8*)(Qp + (qw + l16) * DH_ + cc * 32 + quad * 8);

        facc4 oacc[4] = {};                     // O^T: [dt], row=d, col=q=l16
        float lp = 0.f;                         // per-lane partial denominator

        // prefetch tile 0
        bfrag8 kn[4], vn[4]; int pn;
        kn[0] = *(const bfrag8*)(Kp + l16 * DH_ + quad * 8);
        kn[1] = *(const bfrag8*)(Kp + l16 * DH_ + 32 + quad * 8);
        kn[2] = *(const bfrag8*)(Kp + (16 + l16) * DH_ + quad * 8);
        kn[3] = *(const bfrag8*)(Kp + (16 + l16) * DH_ + 32 + quad * 8);
        pn = pmb[lane & 31];
#pragma unroll
        for (int dt = 0; dt < 4; ++dt)
            vn[dt] = *(const bfrag8*)(Vp + (dt * 16 + l16) * S_ + quad * 8);

        for (int t = 0; t <= c; ++t) {
            int k0 = t * 32;
            bfrag8 kf00 = kn[0], kf01 = kn[1], kf10 = kn[2], kf11 = kn[3];
            int cpm = pn;
            bfrag8 vf[4];
#pragma unroll
            for (int dt = 0; dt < 4; ++dt) vf[dt] = vn[dt];

            if (t < c) {                        // prefetch tile t+1
                int k1 = k0 + 32;
                kn[0] = *(const bfrag8*)(Kp + (k1 + l16) * DH_ + quad * 8);
                kn[1] = *(const bfrag8*)(Kp + (k1 + l16) * DH_ + 32 + quad * 8);
                kn[2] = *(const bfrag8*)(Kp + (k1 + 16 + l16) * DH_ + quad * 8);
                kn[3] = *(const bfrag8*)(Kp + (k1 + 16 + l16) * DH_ + 32 + quad * 8);
                pn = pmb[k1 + (lane & 31)];
#pragma unroll
                for (int dt = 0; dt < 4; ++dt)
                    vn[dt] = *(const bfrag8*)(Vp + (dt * 16 + l16) * S_ + k1 + quad * 8);
            }

            facc4 st[2] = {};                   // S^T (pre-scaled): row=key, col=q
            __builtin_amdgcn_s_setprio(1);
            st[0] = __builtin_amdgcn_mfma_f32_16x16x32_bf16(kf00, qf[0], st[0], 0, 0, 0);
            st[0] = __builtin_amdgcn_mfma_f32_16x16x32_bf16(kf01, qf[1], st[0], 0, 0, 0);
            st[1] = __builtin_amdgcn_mfma_f32_16x16x32_bf16(kf10, qf[0], st[1], 0, 0, 0);
            st[1] = __builtin_amdgcn_mfma_f32_16x16x32_bf16(kf11, qf[1], st[1], 0, 0, 0);
            __builtin_amdgcn_s_setprio(0);

            unsigned vm = (unsigned)__ballot(cpm != 0 && lane < 32);

            if (vm == 0xffffffffu && t < c) {
                // interior, fully valid: zero mask VALU
                float p[8];
#pragma unroll
                for (int kt = 0; kt < 2; ++kt)
#pragma unroll
                    for (int r = 0; r < 4; ++r) p[kt * 4 + r] = st[kt][r];
                soft_pv(p, lp, oacc, vf, a0, a1, qlo);
            } else {
                // diagonal and/or padded tile: per-element causal+pad mask
                float p[8];
#pragma unroll
                for (int kt = 0; kt < 2; ++kt)
#pragma unroll
                    for (int r = 0; r < 4; ++r) {
                        int kl = kt * 16 + quad * 4 + r;
                        bool ok = ((vm >> kl) & 1u) && (k0 + kl <= qw + l16);
                        p[kt * 4 + r] = ok ? st[kt][r] : -1e30f;
                    }
                soft_pv(p, lp, oacc, vf, a0, a1, qlo);
            }
        }

        // finalize: reduce l across quads (once per chunk), normalize, store O^T
        {
            float l = lp;
            l += __shfl_xor(l, 16);
            l += __shfl_xor(l, 32);
            float linv = (l > 0.f) ? 1.f / l : 0.f;
            size_t qoff = (size_t)(qw + l16) * D_;
#pragma unroll
            for (int dt = 0; dt < 4; ++dt) {
                union { u16 hh[4]; u64 q; } pk4;
#pragma unroll
                for (int r = 0; r < 4; ++r) pk4.hh[r] = bfr(oacc[dt][r] * linv);
                *(u64*)(Ao + qoff + dt * 16 + quad * 4) = pk4.q;
            }
        }
    }
}

// ---------------------------------------------------------------------------
extern "C" void kernel_launch(void* const* d_in, const int* in_sizes, int n_in,
                              void* d_out, int out_size, void* d_ws, size_t ws_size,
                              hipStream_t stream) {
    const float* x  = (const float*)d_in[0];
    const float* Wq = (const float*)d_in[1];
    const float* bq = (const float*)d_in[2];
    const float* Wk = (const float*)d_in[3];
    const float* bk = (const float*)d_in[4];
    const float* Wv = (const float*)d_in[5];
    const float* bv = (const float*)d_in[6];
    const float* Wo = (const float*)d_in[7];
    const float* bo = (const float*)d_in[8];
    const int*   pm = (const int*)d_in[9];
    float* out = (float*)d_out;

    char* ws = (char*)d_ws;
    const size_t SZ_XD = (size_t)M_ * D_ * 2;   // 16 MiB bf16 [M,D]
    const size_t SZ_W  = (size_t)D_ * D_ * 2;   //  2 MiB bf16 [D,D]
    u16* X16 = (u16*)ws;                 // reused as attended output (safe: X16's
                                         // last read is the V GEMM; attn writes later)
    u16* WTq = (u16*)(ws + SZ_XD);
    u16* WTk = (u16*)(ws + SZ_XD + SZ_W);
    u16* WTv = (u16*)(ws + SZ_XD + 2 * SZ_W);
    u16* WTo = (u16*)(ws + SZ_XD + 3 * SZ_W);
    u16* Qb  = (u16*)(ws + SZ_XD + 4 * SZ_W);
    u16* Kb  = (u16*)(ws + 2 * SZ_XD + 4 * SZ_W);
    u16* VTb = (u16*)(ws + 3 * SZ_XD + 4 * SZ_W);
    u16* Att = X16;

    cvt_x<<<(M_ * D_) / (256 * 4), 256, 0, stream>>>(x, X16, M_ * D_);
    cvt_wt<<<dim3(D_ / 32, D_ / 32, 4), 256, 0, stream>>>(Wq, Wk, Wv, Wo, WTq, WTk, WTv, WTo);

    gemm_qkv<<<dim3(D_ / 128, M_ / 128, 3), 256, 0, stream>>>(X16, WTq, bq, Qb, WTk, bk, Kb, WTv, bv, VTb);

    attn<<<dim3(16, H_, B_), 256, 0, stream>>>(Qb, Kb, VTb, pm, Att);

    gemm_o<<<dim3(D_ / 128, M_ / 128), 256, 0, stream>>>(Att, WTo, bo, out);
}

// Round 3
// 310.506 us; speedup vs baseline: 1.5287x; 1.5287x over previous
//
#include <hip/hip_runtime.h>
#include <hip/hip_bf16.h>

#define B_   4
#define S_   2048
#define D_   1024
#define H_   16
#define DH_  64
#define M_   (B_ * S_)

typedef __attribute__((ext_vector_type(8))) short  bfrag8;   // 8 bf16 = 4 VGPRs
typedef __attribute__((ext_vector_type(4))) float  facc4;    // 4 fp32 accum
typedef unsigned short u16;
typedef unsigned long long u64;

__device__ __forceinline__ u16 f2bf(float f) {
    union { __hip_bfloat16 h; u16 u; } c;
    c.h = __float2bfloat16(f);
    return c.u;
}

// manual RNE fp32->bf16 (finite inputs only)
__device__ __forceinline__ u16 bfr(float f) {
    unsigned b = __float_as_uint(f);
    return (u16)((b + 0x7FFFu + ((b >> 16) & 1u)) >> 16);
}

// async global->LDS, 16B per lane; LDS dest must be wave-uniform base + lane*16
__device__ __forceinline__ void gl_lds16(const u16* g, u16* l) {
    __builtin_amdgcn_global_load_lds((const __attribute__((address_space(1))) void*)g,
                                     (__attribute__((address_space(3))) void*)l,
                                     16, 0, 0);
}

// ---------------------------------------------------------------------------
// fp32 -> bf16 elementwise convert (x)
// ---------------------------------------------------------------------------
__global__ __launch_bounds__(256) void cvt_x(const float* __restrict__ x,
                                             u16* __restrict__ o, int n) {
    int i = (blockIdx.x * 256 + threadIdx.x) * 4;
    if (i >= n) return;
    float4 v = *(const float4*)(x + i);
    ushort4 r;
    r.x = f2bf(v.x); r.y = f2bf(v.y); r.z = f2bf(v.z); r.w = f2bf(v.w);
    *(ushort4*)(o + i) = r;
}

// ---------------------------------------------------------------------------
// fp32 W[k][n] -> bf16 WT[n][k] transpose+convert, 32x32 LDS tiles.
// ---------------------------------------------------------------------------
__global__ __launch_bounds__(256) void cvt_wt(const float* __restrict__ w0, const float* __restrict__ w1,
                                              const float* __restrict__ w2, const float* __restrict__ w3,
                                              u16* __restrict__ o0, u16* __restrict__ o1,
                                              u16* __restrict__ o2, u16* __restrict__ o3) {
    const float* w; u16* o;
    switch (blockIdx.z) {
        case 0: w = w0; o = o0; break;
        case 1: w = w1; o = o1; break;
        case 2: w = w2; o = o2; break;
        default: w = w3; o = o3; break;
    }
    __shared__ u16 t[32][33];
    int kb = blockIdx.x * 32, nb = blockIdx.y * 32;
    int c = threadIdx.x & 31, r0 = threadIdx.x >> 5;
#pragma unroll
    for (int i = 0; i < 4; i++) {
        int r = r0 + 8 * i;
        t[r][c] = f2bf(w[(kb + r) * D_ + nb + c]);
    }
    __syncthreads();
#pragma unroll
    for (int i = 0; i < 4; i++) {
        int r = r0 + 8 * i;
        o[(nb + r) * D_ + kb + c] = t[c][r];
    }
}

// ---------------------------------------------------------------------------
// pack padding mask to bitmask words: pmw[b*64 + t] bit i <-> key t*32+i valid
// ---------------------------------------------------------------------------
__global__ __launch_bounds__(64) void pack_pm(const int* __restrict__ pm,
                                              unsigned* __restrict__ pmw) {
    int b = blockIdx.x, lane = threadIdx.x;
#pragma unroll
    for (int j = 0; j < 32; ++j) {
        u64 m = __ballot(pm[b * S_ + j * 64 + lane] != 0);
        if (lane == 0) {
            pmw[b * 64 + 2 * j]     = (unsigned)m;
            pmw[b * 64 + 2 * j + 1] = (unsigned)(m >> 32);
        }
    }
}

// ---------------------------------------------------------------------------
// m97-style GEMM body: C[M,N] = (A[M,K] @ BT[N,K]^T + bias) * scale.
// 128x128 tile, BK=32, global_load_lds 16B staging, XOR chunk swizzle.
// ---------------------------------------------------------------------------
__device__ __forceinline__ void gemm_body(const u16* __restrict__ A,
                                          const u16* __restrict__ BT,
                                          const float* __restrict__ bias,
                                          void* __restrict__ Cout, int mode, float scale,
                                          u16* As, u16* Bs) {
    int tid = threadIdx.x;
    int nb = blockIdx.x * 128, mb = blockIdx.y * 128;
    int w = tid >> 6, lane = tid & 63, quad = lane >> 4, l16 = lane & 15;
    int wm = (w >> 1) * 64, wn = (w & 1) * 64;

    int c0 = tid, c1 = tid + 256;
    int row0 = c0 >> 2, row1 = c1 >> 2;
    int sw0 = (c0 & 3) ^ ((row0 >> 2) & 3);
    int sw1 = (c1 & 3) ^ ((row1 >> 2) & 3);
    const u16* Ag0 = A + (mb + row0) * D_ + sw0 * 8;
    const u16* Ag1 = A + (mb + row1) * D_ + sw1 * 8;
    const u16* Bg0 = BT + (nb + row0) * D_ + sw0 * 8;
    const u16* Bg1 = BT + (nb + row1) * D_ + sw1 * 8;
    u16* Al0 = As + c0 * 8; u16* Al1 = As + c1 * 8;
    u16* Bl0 = Bs + c0 * 8; u16* Bl1 = Bs + c1 * 8;

    int swr = (l16 >> 2) & 3;

    facc4 acc[4][4] = {};
    for (int kk = 0; kk < D_; kk += 32) {
        __syncthreads();
        gl_lds16(Ag0 + kk, Al0);
        gl_lds16(Ag1 + kk, Al1);
        gl_lds16(Bg0 + kk, Bl0);
        gl_lds16(Bg1 + kk, Bl1);
        __syncthreads();

        bfrag8 af[4], bf[4];
#pragma unroll
        for (int mt = 0; mt < 4; ++mt)
            af[mt] = *(const bfrag8*)(As + (wm + mt * 16 + l16) * 32 + ((quad ^ swr) << 3));
#pragma unroll
        for (int nt = 0; nt < 4; ++nt)
            bf[nt] = *(const bfrag8*)(Bs + (wn + nt * 16 + l16) * 32 + ((quad ^ swr) << 3));
#pragma unroll
        for (int mt = 0; mt < 4; ++mt)
#pragma unroll
            for (int nt = 0; nt < 4; ++nt)
                acc[mt][nt] = __builtin_amdgcn_mfma_f32_16x16x32_bf16(af[mt], bf[nt], acc[mt][nt], 0, 0, 0);
    }

#pragma unroll
    for (int mt = 0; mt < 4; ++mt) {
        int m_base = mb + wm + mt * 16 + quad * 4;
#pragma unroll
        for (int nt = 0; nt < 4; ++nt) {
            int n = nb + wn + nt * 16 + l16;
            float bv = bias[n];
            int h = n >> 6, dd = n & 63;
#pragma unroll
            for (int r = 0; r < 4; ++r) {
                int m = m_base + r;
                float v = (acc[mt][nt][r] + bv) * scale;
                int bi = m >> 11, s = m & (S_ - 1);
                if (mode == 0) {
                    ((u16*)Cout)[(((bi * H_ + h) * S_) + s) * DH_ + dd] = bfr(v);
                } else if (mode == 1) {
                    ((u16*)Cout)[(((bi * H_ + h) * DH_) + dd) * S_ + s] = bfr(v);
                } else {
                    ((float*)Cout)[(size_t)m * D_ + n] = v;
                }
            }
        }
    }
}

#define CE_Q 0.18033688011112042f   // log2(e)/sqrt(DH), folded into Q

__global__ __launch_bounds__(256) void gemm_qkv(const u16* __restrict__ A,
                                                const u16* __restrict__ WTq, const float* __restrict__ bq, u16* __restrict__ Qb,
                                                const u16* __restrict__ WTk, const float* __restrict__ bk, u16* __restrict__ Kb,
                                                const u16* __restrict__ WTv, const float* __restrict__ bv, u16* __restrict__ VTb) {
    __shared__ u16 As[128 * 32];
    __shared__ u16 Bs[128 * 32];
    switch (blockIdx.z) {
        case 0: gemm_body(A, WTq, bq, Qb, 0, CE_Q, As, Bs); break;   // Q pre-scaled
        case 1: gemm_body(A, WTk, bk, Kb, 0, 1.0f, As, Bs); break;
        default: gemm_body(A, WTv, bv, VTb, 1, 1.0f, As, Bs); break;
    }
}

__global__ __launch_bounds__(256) void gemm_o(const u16* __restrict__ A,
                                              const u16* __restrict__ WTo, const float* __restrict__ bo,
                                              float* __restrict__ out) {
    __shared__ u16 As[128 * 32];
    __shared__ u16 Bs[128 * 32];
    gemm_body(A, WTo, bo, out, 2, 1.0f, As, Bs);
}

// ---------------------------------------------------------------------------
// Flash attention, S^T/O^T formulation, fixed-base softmax.
// R2 post-mortem: kernel is K/V VMEM-bandwidth-bound (per-SIMD iter time
// identical at 2 and 4 waves/SIMD => saturated load path, not latency).
// R2 restructure: block = 128 q-rows of one (b,h), 4 waves x 32 rows each;
// K/V tile (32 keys) staged ONCE per block-iter into LDS via global_load_lds
// and shared by all 4 waves -> 8x VMEM traffic cut.
//  - T2/rule21 XOR swizzle: linear LDS dest, inverse-swizzled GLOBAL source,
//    swizzled ds_read -> b128 reads spread over all 32 banks.
//  - LPT dispatch: long chunks (ci=15) first; bh-affinity: all 16 blocks of
//    one (b,h) share lid&7 -> same XCD L2.
//  - padding mask pre-packed to 32-bit words (pack_pm) -> uniform load/iter.
// Inner math identical to the verified R0 body (same fragment register
// contents, same soft_pv, same store).
// ---------------------------------------------------------------------------
// exp2 + pack + lane-transpose (bpermute) + PV accumulate for one q-tile
__device__ __forceinline__ void soft_pv(const float* p, float& lp, facc4* oaccq,
                                        const bfrag8* vf, int a0, int a1, bool qlo) {
    float rs = 0.f;
    unsigned pk[4];
#pragma unroll
    for (int j = 0; j < 4; ++j) {
        float e0 = exp2f(p[2 * j]);
        float e1 = exp2f(p[2 * j + 1]);
        rs += e0; rs += e1;
        pk[j] = __builtin_amdgcn_perm(__float_as_uint(e1), __float_as_uint(e0), 0x07060302u);
    }
    lp += rs;                                   // per-lane partial; reduced once per chunk
    union { unsigned d[4]; bfrag8 v; } pb;
    {
        unsigned lo, hi;
        lo = __builtin_amdgcn_ds_bpermute(a0, (int)pk[0]);
        hi = __builtin_amdgcn_ds_bpermute(a0, (int)pk[2]);
        pb.d[0] = qlo ? lo : hi;
        lo = __builtin_amdgcn_ds_bpermute(a0, (int)pk[1]);
        hi = __builtin_amdgcn_ds_bpermute(a0, (int)pk[3]);
        pb.d[1] = qlo ? lo : hi;
        lo = __builtin_amdgcn_ds_bpermute(a1, (int)pk[0]);
        hi = __builtin_amdgcn_ds_bpermute(a1, (int)pk[2]);
        pb.d[2] = qlo ? lo : hi;
        lo = __builtin_amdgcn_ds_bpermute(a1, (int)pk[1]);
        hi = __builtin_amdgcn_ds_bpermute(a1, (int)pk[3]);
        pb.d[3] = qlo ? lo : hi;
    }
    __builtin_amdgcn_s_setprio(1);
#pragma unroll
    for (int dt = 0; dt < 4; ++dt)
        oaccq[dt] = __builtin_amdgcn_mfma_f32_16x16x32_bf16(vf[dt], pb.v, oaccq[dt], 0, 0, 0);
    __builtin_amdgcn_s_setprio(0);
}

__global__ __launch_bounds__(256, 4) void attn(const u16* __restrict__ Q,
                                               const u16* __restrict__ K,
                                               const u16* __restrict__ VT,
                                               const unsigned* __restrict__ pmw,
                                               u16* __restrict__ Aout) {
    __shared__ __attribute__((aligned(16))) u16 Ks[32 * 64];   // [key][dh] 4KB
    __shared__ __attribute__((aligned(16))) u16 Vs[64 * 32];   // [d][key] 4KB

    int tid = threadIdx.x, w = tid >> 6, lane = tid & 63;
    int quad = lane >> 4, l16 = lane & 15;

    // lid -> (bh, ci): all 16 blocks of one bh share lid&7 (same XCD);
    // j = lid>>6 ascending => ci = 15-j descending (LPT: long blocks first).
    int lid = blockIdx.x;                       // [0,1024)
    int bh  = (lid & 7) * 8 + ((lid >> 3) & 7); // [0,64)
    int ci  = 15 - (lid >> 6);                  // [0,16) chunk of 128 q-rows
    int b = bh >> 4, h = bh & 15;

    int qbase = ci * 128;
    int qw = qbase + w * 32;                    // this wave's 32 q-rows
    int tmax = (qbase >> 5) + 3;                // tiles 0..tmax (32 keys each)

    const u16* Qp = Q + (size_t)(b * H_ + h) * S_ * DH_;
    const u16* Kp = K + (size_t)(b * H_ + h) * S_ * DH_;
    const u16* Vp = VT + (size_t)(b * H_ + h) * DH_ * S_;
    const unsigned* pmb = pmw + b * 64;
    u16* Ao = Aout + (size_t)b * S_ * D_ + h * DH_;

    // staging thread map (inverse-swizzled global source, linear LDS dest)
    int krow = tid >> 3, ku = tid & 7;          // K tile: 32 rows x 8x16B units
    const u16* Kg = Kp + krow * DH_ + ((ku ^ (krow & 7)) * 8);
    u16* Kl = Ks + tid * 8;
    int vrow = tid >> 2, vu = tid & 3;          // V tile: 64 rows x 4x16B units
    const u16* Vg = Vp + vrow * S_ + ((vu ^ (vrow & 3)) * 8);
    u16* Vl = Vs + tid * 8;

    // swizzled read constants
    int k7 = l16 & 7, v3 = l16 & 3;

    // bpermute byte-addresses for the P^T lane permute (loop-invariant)
    int a0 = ((((2 * quad) & 3) * 16 + l16) << 2);
    int a1 = ((((2 * quad + 1) & 3) * 16 + l16) << 2);
    bool qlo = quad < 2;

    bfrag8 qf[2][2];
#pragma unroll
    for (int qt = 0; qt < 2; ++qt)
#pragma unroll
        for (int cc = 0; cc < 2; ++cc)
            qf[qt][cc] = *(const bfrag8*)(Qp + (qw + qt * 16 + l16) * DH_ + cc * 32 + quad * 8);

    facc4 oacc[2][4] = {};                      // O^T: [qt][dt], row=d, col=q=l16
    float lp[2] = {0.f, 0.f};                   // per-lane partial denominators

    for (int t = 0; t <= tmax; ++t) {
        int k0 = t * 32;
        __syncthreads();                        // prior tile's readers done
        gl_lds16(Kg + k0 * DH_, Kl);
        gl_lds16(Vg + k0, Vl);
        __syncthreads();                        // staged data visible

        // K fragments from LDS (swizzled read; contents == R0's global frags)
        bfrag8 kf00 = *(const bfrag8*)(Ks + (l16 * 8        + ((quad)     ^ k7)) * 8);
        bfrag8 kf01 = *(const bfrag8*)(Ks + (l16 * 8        + ((quad + 4) ^ k7)) * 8);
        bfrag8 kf10 = *(const bfrag8*)(Ks + ((l16 + 16) * 8 + ((quad)     ^ k7)) * 8);
        bfrag8 kf11 = *(const bfrag8*)(Ks + ((l16 + 16) * 8 + ((quad + 4) ^ k7)) * 8);
        bfrag8 vf[4];
#pragma unroll
        for (int dt = 0; dt < 4; ++dt)
            vf[dt] = *(const bfrag8*)(Vs + ((dt * 16 + l16) * 4 + (quad ^ v3)) * 8);

        unsigned vm = pmb[t];

        facc4 st[2][2] = {};                    // S^T (pre-scaled): row=key, col=q
        __builtin_amdgcn_s_setprio(1);
#pragma unroll
        for (int qt = 0; qt < 2; ++qt) {
            st[qt][0] = __builtin_amdgcn_mfma_f32_16x16x32_bf16(kf00, qf[qt][0], st[qt][0], 0, 0, 0);
            st[qt][0] = __builtin_amdgcn_mfma_f32_16x16x32_bf16(kf01, qf[qt][1], st[qt][0], 0, 0, 0);
            st[qt][1] = __builtin_amdgcn_mfma_f32_16x16x32_bf16(kf10, qf[qt][0], st[qt][1], 0, 0, 0);
            st[qt][1] = __builtin_amdgcn_mfma_f32_16x16x32_bf16(kf11, qf[qt][1], st[qt][1], 0, 0, 0);
        }
        __builtin_amdgcn_s_setprio(0);

        if (vm == 0xffffffffu && k0 + 31 < qw) {
            // interior, fully valid: zero mask VALU
#pragma unroll
            for (int qt = 0; qt < 2; ++qt) {
                float p[8];
#pragma unroll
                for (int kt = 0; kt < 2; ++kt)
#pragma unroll
                    for (int r = 0; r < 4; ++r) p[kt * 4 + r] = st[qt][kt][r];
                soft_pv(p, lp[qt], oacc[qt], vf, a0, a1, qlo);
            }
        } else {
            // diagonal / padded / above-diagonal tile: per-element mask
#pragma unroll
            for (int qt = 0; qt < 2; ++qt) {
                int q0 = qw + qt * 16;
                float p[8];
#pragma unroll
                for (int kt = 0; kt < 2; ++kt)
#pragma unroll
                    for (int r = 0; r < 4; ++r) {
                        int kl = kt * 16 + quad * 4 + r;
                        bool ok = ((vm >> kl) & 1u) && (k0 + kl <= q0 + l16);
                        p[kt * 4 + r] = ok ? st[qt][kt][r] : -1e30f;
                    }
                soft_pv(p, lp[qt], oacc[qt], vf, a0, a1, qlo);
            }
        }
    }

    // finalize: reduce l across quads, normalize, store O^T
#pragma unroll
    for (int qt = 0; qt < 2; ++qt) {
        float l = lp[qt];
        l += __shfl_xor(l, 16);
        l += __shfl_xor(l, 32);
        float linv = (l > 0.f) ? 1.f / l : 0.f;
        size_t qoff = (size_t)(qw + qt * 16 + l16) * D_;
#pragma unroll
        for (int dt = 0; dt < 4; ++dt) {
            union { u16 hh[4]; u64 q; } pk4;
#pragma unroll
            for (int r = 0; r < 4; ++r) pk4.hh[r] = bfr(oacc[qt][dt][r] * linv);
            *(u64*)(Ao + qoff + dt * 16 + quad * 4) = pk4.q;
        }
    }
}

// ---------------------------------------------------------------------------
extern "C" void kernel_launch(void* const* d_in, const int* in_sizes, int n_in,
                              void* d_out, int out_size, void* d_ws, size_t ws_size,
                              hipStream_t stream) {
    const float* x  = (const float*)d_in[0];
    const float* Wq = (const float*)d_in[1];
    const float* bq = (const float*)d_in[2];
    const float* Wk = (const float*)d_in[3];
    const float* bk = (const float*)d_in[4];
    const float* Wv = (const float*)d_in[5];
    const float* bv = (const float*)d_in[6];
    const float* Wo = (const float*)d_in[7];
    const float* bo = (const float*)d_in[8];
    const int*   pm = (const int*)d_in[9];
    float* out = (float*)d_out;

    char* ws = (char*)d_ws;
    const size_t SZ_XD = (size_t)M_ * D_ * 2;   // 16 MiB bf16 [M,D]
    const size_t SZ_W  = (size_t)D_ * D_ * 2;   //  2 MiB bf16 [D,D]
    u16* X16 = (u16*)ws;                 // reused as attended output (safe: X16's
                                         // last read is the V GEMM; attn writes later)
    u16* WTq = (u16*)(ws + SZ_XD);
    u16* WTk = (u16*)(ws + SZ_XD + SZ_W);
    u16* WTv = (u16*)(ws + SZ_XD + 2 * SZ_W);
    u16* WTo = (u16*)(ws + SZ_XD + 3 * SZ_W);
    u16* Qb  = (u16*)(ws + SZ_XD + 4 * SZ_W);
    u16* Kb  = (u16*)(ws + 2 * SZ_XD + 4 * SZ_W);
    u16* VTb = (u16*)(ws + 3 * SZ_XD + 4 * SZ_W);
    u16* Att = X16;
    unsigned* PMW = (unsigned*)WTq;      // WTq dead after gemm_qkv; pack_pm runs after

    cvt_x<<<(M_ * D_) / (256 * 4), 256, 0, stream>>>(x, X16, M_ * D_);
    cvt_wt<<<dim3(D_ / 32, D_ / 32, 4), 256, 0, stream>>>(Wq, Wk, Wv, Wo, WTq, WTk, WTv, WTo);

    gemm_qkv<<<dim3(D_ / 128, M_ / 128, 3), 256, 0, stream>>>(X16, WTq, bq, Qb, WTk, bk, Kb, WTv, bv, VTb);

    pack_pm<<<4, 64, 0, stream>>>(pm, PMW);

    attn<<<dim3(1024), 256, 0, stream>>>(Qb, Kb, VTb, PMW, Att);

    gemm_o<<<dim3(D_ / 128, M_ / 128), 256, 0, stream>>>(Att, WTo, bo, out);
}

// Round 4
// 296.923 us; speedup vs baseline: 1.5986x; 1.0457x over previous
//
#include <hip/hip_runtime.h>
#include <hip/hip_bf16.h>

#define B_   4
#define S_   2048
#define D_   1024
#define H_   16
#define DH_  64
#define M_   (B_ * S_)

typedef __attribute__((ext_vector_type(8))) short  bfrag8;   // 8 bf16 = 4 VGPRs
typedef __attribute__((ext_vector_type(4))) float  facc4;    // 4 fp32 accum
typedef unsigned short u16;
typedef unsigned long long u64;

__device__ __forceinline__ u16 f2bf(float f) {
    union { __hip_bfloat16 h; u16 u; } c;
    c.h = __float2bfloat16(f);
    return c.u;
}

// manual RNE fp32->bf16 (finite inputs only)
__device__ __forceinline__ u16 bfr(float f) {
    unsigned b = __float_as_uint(f);
    return (u16)((b + 0x7FFFu + ((b >> 16) & 1u)) >> 16);
}

// async global->LDS, 16B per lane; LDS dest must be wave-uniform base + lane*16
__device__ __forceinline__ void gl_lds16(const u16* g, u16* l) {
    __builtin_amdgcn_global_load_lds((const __attribute__((address_space(1))) void*)g,
                                     (__attribute__((address_space(3))) void*)l,
                                     16, 0, 0);
}

// ---------------------------------------------------------------------------
// fp32 -> bf16 elementwise convert (x)
// ---------------------------------------------------------------------------
__global__ __launch_bounds__(256) void cvt_x(const float* __restrict__ x,
                                             u16* __restrict__ o, int n) {
    int i = (blockIdx.x * 256 + threadIdx.x) * 4;
    if (i >= n) return;
    float4 v = *(const float4*)(x + i);
    ushort4 r;
    r.x = f2bf(v.x); r.y = f2bf(v.y); r.z = f2bf(v.z); r.w = f2bf(v.w);
    *(ushort4*)(o + i) = r;
}

// ---------------------------------------------------------------------------
// fp32 W[k][n] -> bf16 WT[n][k] transpose+convert, 32x32 LDS tiles.
// ---------------------------------------------------------------------------
__global__ __launch_bounds__(256) void cvt_wt(const float* __restrict__ w0, const float* __restrict__ w1,
                                              const float* __restrict__ w2, const float* __restrict__ w3,
                                              u16* __restrict__ o0, u16* __restrict__ o1,
                                              u16* __restrict__ o2, u16* __restrict__ o3) {
    const float* w; u16* o;
    switch (blockIdx.z) {
        case 0: w = w0; o = o0; break;
        case 1: w = w1; o = o1; break;
        case 2: w = w2; o = o2; break;
        default: w = w3; o = o3; break;
    }
    __shared__ u16 t[32][33];
    int kb = blockIdx.x * 32, nb = blockIdx.y * 32;
    int c = threadIdx.x & 31, r0 = threadIdx.x >> 5;
#pragma unroll
    for (int i = 0; i < 4; i++) {
        int r = r0 + 8 * i;
        t[r][c] = f2bf(w[(kb + r) * D_ + nb + c]);
    }
    __syncthreads();
#pragma unroll
    for (int i = 0; i < 4; i++) {
        int r = r0 + 8 * i;
        o[(nb + r) * D_ + kb + c] = t[c][r];
    }
}

// ---------------------------------------------------------------------------
// pack padding mask to bitmask words: pmw[b*64 + t] bit i <-> key t*32+i valid
// ---------------------------------------------------------------------------
__global__ __launch_bounds__(64) void pack_pm(const int* __restrict__ pm,
                                              unsigned* __restrict__ pmw) {
    int b = blockIdx.x, lane = threadIdx.x;
#pragma unroll
    for (int j = 0; j < 32; ++j) {
        u64 m = __ballot(pm[b * S_ + j * 64 + lane] != 0);
        if (lane == 0) {
            pmw[b * 64 + 2 * j]     = (unsigned)m;
            pmw[b * 64 + 2 * j + 1] = (unsigned)(m >> 32);
        }
    }
}

// ---------------------------------------------------------------------------
// R3 GEMM: C[M,N] = (A[M,K] @ BT[N,K]^T + bias) * scale.
// BM=256 x BN=128 x BK=64, 512 threads / 8 waves (4M x 2N), double-buffered
// 96KB LDS, T3-minimal pipeline: stage tile t+1 BEFORE compute of tile t,
// single asm vmcnt(0) + raw s_barrier per K-tile (loads get the whole MFMA
// phase to land; no per-phase compiler vmcnt(0)-drain). T2 XOR swizzle via
// inverse-swizzled GLOBAL source + linear LDS dest (R2-verified pattern),
// swizzled ds_read_b128 -> conflict-free. T5 setprio around MFMA clusters.
// K-accumulation order identical to the previous passing kernel.
// ---------------------------------------------------------------------------
#define ABUF_ (256 * 64)            // u16 per A region
#define TBUF_ ((256 + 128) * 64)    // u16 per buffer (A + B)

__device__ __forceinline__ void gemm_body256(const u16* __restrict__ A,
                                             const u16* __restrict__ BT,
                                             const float* __restrict__ bias,
                                             void* __restrict__ Cout, int mode, float scale,
                                             u16* S) {
    int tid = threadIdx.x;
    int nb = blockIdx.x * 128, mb = blockIdx.y * 256;
    int w = tid >> 6, lane = tid & 63, quad = lane >> 4, l16 = lane & 15;
    int wm = (w >> 1) * 64, wn = (w & 1) * 64;
    int x7 = l16 & 7;

    // staging source pointers (inverse-swizzled global, linear LDS dest)
    const u16* Aga[4]; const u16* Bga[2];
#pragma unroll
    for (int i = 0; i < 4; ++i) {
        int idx = i * 512 + tid, row = idx >> 3;
        int lu = (idx & 7) ^ (row & 7);
        Aga[i] = A + (size_t)(mb + row) * D_ + lu * 8;
    }
#pragma unroll
    for (int i = 0; i < 2; ++i) {
        int idx = i * 512 + tid, row = idx >> 3;
        int lu = (idx & 7) ^ (row & 7);
        Bga[i] = BT + (size_t)(nb + row) * D_ + lu * 8;
    }

    facc4 acc[4][4] = {};

    // prologue: stage K-tile 0 into buffer 0
#pragma unroll
    for (int i = 0; i < 4; ++i) gl_lds16(Aga[i], S + (i * 512 + tid) * 8);
#pragma unroll
    for (int i = 0; i < 2; ++i) gl_lds16(Bga[i], S + ABUF_ + (i * 512 + tid) * 8);
    asm volatile("s_waitcnt vmcnt(0)" ::: "memory");
    __builtin_amdgcn_sched_barrier(0);
    __builtin_amdgcn_s_barrier();
    __builtin_amdgcn_sched_barrier(0);

    for (int kt = 0; kt < 16; ++kt) {
        u16* Cb = S + (kt & 1) * TBUF_;           // current (staged, ready)
        u16* Nb = S + ((kt & 1) ^ 1) * TBUF_;     // next (fully consumed last iter)
        if (kt < 15) {                            // issue next-tile stage first
            int ko = (kt + 1) * 64;
#pragma unroll
            for (int i = 0; i < 4; ++i) gl_lds16(Aga[i] + ko, Nb + (i * 512 + tid) * 8);
#pragma unroll
            for (int i = 0; i < 2; ++i) gl_lds16(Bga[i] + ko, Nb + ABUF_ + (i * 512 + tid) * 8);
        }
#pragma unroll
        for (int k2 = 0; k2 < 2; ++k2) {
            int pu = ((k2 * 4 + quad) ^ x7) * 8;  // swizzled 16B-unit offset
            bfrag8 af[4], bf[4];
#pragma unroll
            for (int mt = 0; mt < 4; ++mt)
                af[mt] = *(const bfrag8*)(Cb + (wm + mt * 16 + l16) * 64 + pu);
#pragma unroll
            for (int nt = 0; nt < 4; ++nt)
                bf[nt] = *(const bfrag8*)(Cb + ABUF_ + (wn + nt * 16 + l16) * 64 + pu);
            __builtin_amdgcn_s_setprio(1);
#pragma unroll
            for (int mt = 0; mt < 4; ++mt)
#pragma unroll
                for (int nt = 0; nt < 4; ++nt)
                    acc[mt][nt] = __builtin_amdgcn_mfma_f32_16x16x32_bf16(af[mt], bf[nt], acc[mt][nt], 0, 0, 0);
            __builtin_amdgcn_s_setprio(0);
        }
        // single drain+barrier per K-tile: next tile is now fully landed
        asm volatile("s_waitcnt vmcnt(0)" ::: "memory");
        __builtin_amdgcn_sched_barrier(0);
        __builtin_amdgcn_s_barrier();
        __builtin_amdgcn_sched_barrier(0);
    }

#pragma unroll
    for (int mt = 0; mt < 4; ++mt) {
        int m_base = mb + wm + mt * 16 + quad * 4;
#pragma unroll
        for (int nt = 0; nt < 4; ++nt) {
            int n = nb + wn + nt * 16 + l16;
            float bv = bias[n];
            int h = n >> 6, dd = n & 63;
#pragma unroll
            for (int r = 0; r < 4; ++r) {
                int m = m_base + r;
                float v = (acc[mt][nt][r] + bv) * scale;
                int bi = m >> 11, s = m & (S_ - 1);
                if (mode == 0) {
                    ((u16*)Cout)[(((bi * H_ + h) * S_) + s) * DH_ + dd] = bfr(v);
                } else if (mode == 1) {
                    ((u16*)Cout)[(((bi * H_ + h) * DH_) + dd) * S_ + s] = bfr(v);
                } else {
                    ((float*)Cout)[(size_t)m * D_ + n] = v;
                }
            }
        }
    }
}

#define CE_Q 0.18033688011112042f   // log2(e)/sqrt(DH), folded into Q

__global__ __launch_bounds__(512, 2) void gemm_qkv(const u16* __restrict__ A,
                                                const u16* __restrict__ WTq, const float* __restrict__ bq, u16* __restrict__ Qb,
                                                const u16* __restrict__ WTk, const float* __restrict__ bk, u16* __restrict__ Kb,
                                                const u16* __restrict__ WTv, const float* __restrict__ bv, u16* __restrict__ VTb) {
    __shared__ __attribute__((aligned(16))) u16 Sh[2 * TBUF_];   // 96 KiB
    switch (blockIdx.z) {
        case 0: gemm_body256(A, WTq, bq, Qb, 0, CE_Q, Sh); break;   // Q pre-scaled
        case 1: gemm_body256(A, WTk, bk, Kb, 0, 1.0f, Sh); break;
        default: gemm_body256(A, WTv, bv, VTb, 1, 1.0f, Sh); break;
    }
}

__global__ __launch_bounds__(512, 2) void gemm_o(const u16* __restrict__ A,
                                              const u16* __restrict__ WTo, const float* __restrict__ bo,
                                              float* __restrict__ out) {
    __shared__ __attribute__((aligned(16))) u16 Sh[2 * TBUF_];   // 96 KiB
    gemm_body256(A, WTo, bo, out, 2, 1.0f, Sh);
}

// ---------------------------------------------------------------------------
// Flash attention, S^T/O^T formulation, fixed-base softmax.
// Block = 128 q-rows of one (b,h), 4 waves x 32 rows each; K/V tile (32 keys)
// staged once per block-iter into LDS (global_load_lds) and shared by all
// 4 waves. XOR swizzle via inverse-swizzled global source. LPT dispatch,
// bh-affinity XCD swizzle, pre-packed padding bitmask. (R2, verified)
// ---------------------------------------------------------------------------
// exp2 + pack + lane-transpose (bpermute) + PV accumulate for one q-tile
__device__ __forceinline__ void soft_pv(const float* p, float& lp, facc4* oaccq,
                                        const bfrag8* vf, int a0, int a1, bool qlo) {
    float rs = 0.f;
    unsigned pk[4];
#pragma unroll
    for (int j = 0; j < 4; ++j) {
        float e0 = exp2f(p[2 * j]);
        float e1 = exp2f(p[2 * j + 1]);
        rs += e0; rs += e1;
        pk[j] = __builtin_amdgcn_perm(__float_as_uint(e1), __float_as_uint(e0), 0x07060302u);
    }
    lp += rs;                                   // per-lane partial; reduced once per chunk
    union { unsigned d[4]; bfrag8 v; } pb;
    {
        unsigned lo, hi;
        lo = __builtin_amdgcn_ds_bpermute(a0, (int)pk[0]);
        hi = __builtin_amdgcn_ds_bpermute(a0, (int)pk[2]);
        pb.d[0] = qlo ? lo : hi;
        lo = __builtin_amdgcn_ds_bpermute(a0, (int)pk[1]);
        hi = __builtin_amdgcn_ds_bpermute(a0, (int)pk[3]);
        pb.d[1] = qlo ? lo : hi;
        lo = __builtin_amdgcn_ds_bpermute(a1, (int)pk[0]);
        hi = __builtin_amdgcn_ds_bpermute(a1, (int)pk[2]);
        pb.d[2] = qlo ? lo : hi;
        lo = __builtin_amdgcn_ds_bpermute(a1, (int)pk[1]);
        hi = __builtin_amdgcn_ds_bpermute(a1, (int)pk[3]);
        pb.d[3] = qlo ? lo : hi;
    }
    __builtin_amdgcn_s_setprio(1);
#pragma unroll
    for (int dt = 0; dt < 4; ++dt)
        oaccq[dt] = __builtin_amdgcn_mfma_f32_16x16x32_bf16(vf[dt], pb.v, oaccq[dt], 0, 0, 0);
    __builtin_amdgcn_s_setprio(0);
}

__global__ __launch_bounds__(256, 4) void attn(const u16* __restrict__ Q,
                                               const u16* __restrict__ K,
                                               const u16* __restrict__ VT,
                                               const unsigned* __restrict__ pmw,
                                               u16* __restrict__ Aout) {
    __shared__ __attribute__((aligned(16))) u16 Ks[32 * 64];   // [key][dh] 4KB
    __shared__ __attribute__((aligned(16))) u16 Vs[64 * 32];   // [d][key] 4KB

    int tid = threadIdx.x, w = tid >> 6, lane = tid & 63;
    int quad = lane >> 4, l16 = lane & 15;

    // lid -> (bh, ci): all 16 blocks of one bh share lid&7 (same XCD);
    // j = lid>>6 ascending => ci = 15-j descending (LPT: long blocks first).
    int lid = blockIdx.x;                       // [0,1024)
    int bh  = (lid & 7) * 8 + ((lid >> 3) & 7); // [0,64)
    int ci  = 15 - (lid >> 6);                  // [0,16) chunk of 128 q-rows
    int b = bh >> 4, h = bh & 15;

    int qbase = ci * 128;
    int qw = qbase + w * 32;                    // this wave's 32 q-rows
    int tmax = (qbase >> 5) + 3;                // tiles 0..tmax (32 keys each)

    const u16* Qp = Q + (size_t)(b * H_ + h) * S_ * DH_;
    const u16* Kp = K + (size_t)(b * H_ + h) * S_ * DH_;
    const u16* Vp = VT + (size_t)(b * H_ + h) * DH_ * S_;
    const unsigned* pmb = pmw + b * 64;
    u16* Ao = Aout + (size_t)b * S_ * D_ + h * DH_;

    // staging thread map (inverse-swizzled global source, linear LDS dest)
    int krow = tid >> 3, ku = tid & 7;          // K tile: 32 rows x 8x16B units
    const u16* Kg = Kp + krow * DH_ + ((ku ^ (krow & 7)) * 8);
    u16* Kl = Ks + tid * 8;
    int vrow = tid >> 2, vu = tid & 3;          // V tile: 64 rows x 4x16B units
    const u16* Vg = Vp + vrow * S_ + ((vu ^ (vrow & 3)) * 8);
    u16* Vl = Vs + tid * 8;

    // swizzled read constants
    int k7 = l16 & 7, v3 = l16 & 3;

    // bpermute byte-addresses for the P^T lane permute (loop-invariant)
    int a0 = ((((2 * quad) & 3) * 16 + l16) << 2);
    int a1 = ((((2 * quad + 1) & 3) * 16 + l16) << 2);
    bool qlo = quad < 2;

    bfrag8 qf[2][2];
#pragma unroll
    for (int qt = 0; qt < 2; ++qt)
#pragma unroll
        for (int cc = 0; cc < 2; ++cc)
            qf[qt][cc] = *(const bfrag8*)(Qp + (qw + qt * 16 + l16) * DH_ + cc * 32 + quad * 8);

    facc4 oacc[2][4] = {};                      // O^T: [qt][dt], row=d, col=q=l16
    float lp[2] = {0.f, 0.f};                   // per-lane partial denominators

    for (int t = 0; t <= tmax; ++t) {
        int k0 = t * 32;
        __syncthreads();                        // prior tile's readers done
        gl_lds16(Kg + k0 * DH_, Kl);
        gl_lds16(Vg + k0, Vl);
        __syncthreads();                        // staged data visible

        // K fragments from LDS (swizzled read; contents == R0's global frags)
        bfrag8 kf00 = *(const bfrag8*)(Ks + (l16 * 8        + ((quad)     ^ k7)) * 8);
        bfrag8 kf01 = *(const bfrag8*)(Ks + (l16 * 8        + ((quad + 4) ^ k7)) * 8);
        bfrag8 kf10 = *(const bfrag8*)(Ks + ((l16 + 16) * 8 + ((quad)     ^ k7)) * 8);
        bfrag8 kf11 = *(const bfrag8*)(Ks + ((l16 + 16) * 8 + ((quad + 4) ^ k7)) * 8);
        bfrag8 vf[4];
#pragma unroll
        for (int dt = 0; dt < 4; ++dt)
            vf[dt] = *(const bfrag8*)(Vs + ((dt * 16 + l16) * 4 + (quad ^ v3)) * 8);

        unsigned vm = pmb[t];

        facc4 st[2][2] = {};                    // S^T (pre-scaled): row=key, col=q
        __builtin_amdgcn_s_setprio(1);
#pragma unroll
        for (int qt = 0; qt < 2; ++qt) {
            st[qt][0] = __builtin_amdgcn_mfma_f32_16x16x32_bf16(kf00, qf[qt][0], st[qt][0], 0, 0, 0);
            st[qt][0] = __builtin_amdgcn_mfma_f32_16x16x32_bf16(kf01, qf[qt][1], st[qt][0], 0, 0, 0);
            st[qt][1] = __builtin_amdgcn_mfma_f32_16x16x32_bf16(kf10, qf[qt][0], st[qt][1], 0, 0, 0);
            st[qt][1] = __builtin_amdgcn_mfma_f32_16x16x32_bf16(kf11, qf[qt][1], st[qt][1], 0, 0, 0);
        }
        __builtin_amdgcn_s_setprio(0);

        if (vm == 0xffffffffu && k0 + 31 < qw) {
            // interior, fully valid: zero mask VALU
#pragma unroll
            for (int qt = 0; qt < 2; ++qt) {
                float p[8];
#pragma unroll
                for (int kt = 0; kt < 2; ++kt)
#pragma unroll
                    for (int r = 0; r < 4; ++r) p[kt * 4 + r] = st[qt][kt][r];
                soft_pv(p, lp[qt], oacc[qt], vf, a0, a1, qlo);
            }
        } else {
            // diagonal / padded / above-diagonal tile: per-element mask
#pragma unroll
            for (int qt = 0; qt < 2; ++qt) {
                int q0 = qw + qt * 16;
                float p[8];
#pragma unroll
                for (int kt = 0; kt < 2; ++kt)
#pragma unroll
                    for (int r = 0; r < 4; ++r) {
                        int kl = kt * 16 + quad * 4 + r;
                        bool ok = ((vm >> kl) & 1u) && (k0 + kl <= q0 + l16);
                        p[kt * 4 + r] = ok ? st[qt][kt][r] : -1e30f;
                    }
                soft_pv(p, lp[qt], oacc[qt], vf, a0, a1, qlo);
            }
        }
    }

    // finalize: reduce l across quads, normalize, store O^T
#pragma unroll
    for (int qt = 0; qt < 2; ++qt) {
        float l = lp[qt];
        l += __shfl_xor(l, 16);
        l += __shfl_xor(l, 32);
        float linv = (l > 0.f) ? 1.f / l : 0.f;
        size_t qoff = (size_t)(qw + qt * 16 + l16) * D_;
#pragma unroll
        for (int dt = 0; dt < 4; ++dt) {
            union { u16 hh[4]; u64 q; } pk4;
#pragma unroll
            for (int r = 0; r < 4; ++r) pk4.hh[r] = bfr(oacc[qt][dt][r] * linv);
            *(u64*)(Ao + qoff + dt * 16 + quad * 4) = pk4.q;
        }
    }
}

// ---------------------------------------------------------------------------
extern "C" void kernel_launch(void* const* d_in, const int* in_sizes, int n_in,
                              void* d_out, int out_size, void* d_ws, size_t ws_size,
                              hipStream_t stream) {
    const float* x  = (const float*)d_in[0];
    const float* Wq = (const float*)d_in[1];
    const float* bq = (const float*)d_in[2];
    const float* Wk = (const float*)d_in[3];
    const float* bk = (const float*)d_in[4];
    const float* Wv = (const float*)d_in[5];
    const float* bv = (const float*)d_in[6];
    const float* Wo = (const float*)d_in[7];
    const float* bo = (const float*)d_in[8];
    const int*   pm = (const int*)d_in[9];
    float* out = (float*)d_out;

    char* ws = (char*)d_ws;
    const size_t SZ_XD = (size_t)M_ * D_ * 2;   // 16 MiB bf16 [M,D]
    const size_t SZ_W  = (size_t)D_ * D_ * 2;   //  2 MiB bf16 [D,D]
    u16* X16 = (u16*)ws;                 // reused as attended output (safe: X16's
                                         // last read is the V GEMM; attn writes later)
    u16* WTq = (u16*)(ws + SZ_XD);
    u16* WTk = (u16*)(ws + SZ_XD + SZ_W);
    u16* WTv = (u16*)(ws + SZ_XD + 2 * SZ_W);
    u16* WTo = (u16*)(ws + SZ_XD + 3 * SZ_W);
    u16* Qb  = (u16*)(ws + SZ_XD + 4 * SZ_W);
    u16* Kb  = (u16*)(ws + 2 * SZ_XD + 4 * SZ_W);
    u16* VTb = (u16*)(ws + 3 * SZ_XD + 4 * SZ_W);
    u16* Att = X16;
    unsigned* PMW = (unsigned*)WTq;      // WTq dead after gemm_qkv; pack_pm runs after

    cvt_x<<<(M_ * D_) / (256 * 4), 256, 0, stream>>>(x, X16, M_ * D_);
    cvt_wt<<<dim3(D_ / 32, D_ / 32, 4), 256, 0, stream>>>(Wq, Wk, Wv, Wo, WTq, WTk, WTv, WTo);

    gemm_qkv<<<dim3(D_ / 128, M_ / 256, 3), 512, 0, stream>>>(X16, WTq, bq, Qb, WTk, bk, Kb, WTv, bv, VTb);

    pack_pm<<<4, 64, 0, stream>>>(pm, PMW);

    attn<<<dim3(1024), 256, 0, stream>>>(Qb, Kb, VTb, PMW, Att);

    gemm_o<<<dim3(D_ / 128, M_ / 256), 512, 0, stream>>>(Att, WTo, bo, out);
}

// Round 5
// 279.294 us; speedup vs baseline: 1.6995x; 1.0631x over previous
//
#include <hip/hip_runtime.h>
#include <hip/hip_bf16.h>

#define B_   4
#define S_   2048
#define D_   1024
#define H_   16
#define DH_  64
#define M_   (B_ * S_)

typedef __attribute__((ext_vector_type(8))) short  bfrag8;   // 8 bf16 = 4 VGPRs
typedef __attribute__((ext_vector_type(4))) float  facc4;    // 4 fp32 accum
typedef unsigned short u16;
typedef unsigned long long u64;

__device__ __forceinline__ u16 f2bf(float f) {
    union { __hip_bfloat16 h; u16 u; } c;
    c.h = __float2bfloat16(f);
    return c.u;
}

// manual RNE fp32->bf16 (finite inputs only)
__device__ __forceinline__ u16 bfr(float f) {
    unsigned b = __float_as_uint(f);
    return (u16)((b + 0x7FFFu + ((b >> 16) & 1u)) >> 16);
}

// async global->LDS, 16B per lane; LDS dest must be wave-uniform base + lane*16
__device__ __forceinline__ void gl_lds16(const u16* g, u16* l) {
    __builtin_amdgcn_global_load_lds((const __attribute__((address_space(1))) void*)g,
                                     (__attribute__((address_space(3))) void*)l,
                                     16, 0, 0);
}

// ---------------------------------------------------------------------------
// fp32 -> bf16 elementwise convert (x)
// ---------------------------------------------------------------------------
__global__ __launch_bounds__(256) void cvt_x(const float* __restrict__ x,
                                             u16* __restrict__ o, int n) {
    int i = (blockIdx.x * 256 + threadIdx.x) * 4;
    if (i >= n) return;
    float4 v = *(const float4*)(x + i);
    ushort4 r;
    r.x = f2bf(v.x); r.y = f2bf(v.y); r.z = f2bf(v.z); r.w = f2bf(v.w);
    *(ushort4*)(o + i) = r;
}

// ---------------------------------------------------------------------------
// fp32 W[k][n] -> bf16 WT[n][k] transpose+convert, 32x32 LDS tiles.
// ---------------------------------------------------------------------------
__global__ __launch_bounds__(256) void cvt_wt(const float* __restrict__ w0, const float* __restrict__ w1,
                                              const float* __restrict__ w2, const float* __restrict__ w3,
                                              u16* __restrict__ o0, u16* __restrict__ o1,
                                              u16* __restrict__ o2, u16* __restrict__ o3) {
    const float* w; u16* o;
    switch (blockIdx.z) {
        case 0: w = w0; o = o0; break;
        case 1: w = w1; o = o1; break;
        case 2: w = w2; o = o2; break;
        default: w = w3; o = o3; break;
    }
    __shared__ u16 t[32][33];
    int kb = blockIdx.x * 32, nb = blockIdx.y * 32;
    int c = threadIdx.x & 31, r0 = threadIdx.x >> 5;
#pragma unroll
    for (int i = 0; i < 4; i++) {
        int r = r0 + 8 * i;
        t[r][c] = f2bf(w[(kb + r) * D_ + nb + c]);
    }
    __syncthreads();
#pragma unroll
    for (int i = 0; i < 4; i++) {
        int r = r0 + 8 * i;
        o[(nb + r) * D_ + kb + c] = t[c][r];
    }
}

// ---------------------------------------------------------------------------
// pack padding mask to bitmask words: pmw[b*64 + t] bit i <-> key t*32+i valid
// ---------------------------------------------------------------------------
__global__ __launch_bounds__(64) void pack_pm(const int* __restrict__ pm,
                                              unsigned* __restrict__ pmw) {
    int b = blockIdx.x, lane = threadIdx.x;
#pragma unroll
    for (int j = 0; j < 32; ++j) {
        u64 m = __ballot(pm[b * S_ + j * 64 + lane] != 0);
        if (lane == 0) {
            pmw[b * 64 + 2 * j]     = (unsigned)m;
            pmw[b * 64 + 2 * j + 1] = (unsigned)(m >> 32);
        }
    }
}

// ---------------------------------------------------------------------------
// R4 GEMM: C[M,N] = (A[M,K] @ BT[N,K]^T + bias) * scale.
// BM=256 x BN=128 x BK=64, 512 threads / 8 waves, double-buffered 96KB LDS,
// stage-before-compute, one vmcnt(0)+s_barrier per K-tile (R3 structure).
// R4: T1 XCD panel-affinity swizzle. R3 counters showed the limiter is
// L2-fill bandwidth (2.7 TB/s, FETCH 200MB vs 22MB unique): the 8 N-blocks
// sharing an A-panel had consecutive IDs -> 8 different XCDs -> 8x dup fills.
// Remap (1D grid): xcd = lid&7 owns M-panels y in [xcd*4, xcd*4+4) for all
// x, all z. Concurrent per-XCD set = A 2MB + B 2MB = 4MB = one L2. A-panels
// now have ZERO cross-XCD duplication.
// ---------------------------------------------------------------------------
#define ABUF_ (256 * 64)            // u16 per A region
#define TBUF_ ((256 + 128) * 64)    // u16 per buffer (A + B)

__device__ __forceinline__ void gemm_body256(const u16* __restrict__ A,
                                             const u16* __restrict__ BT,
                                             const float* __restrict__ bias,
                                             void* __restrict__ Cout, int mode, float scale,
                                             u16* S, int nb, int mb) {
    int tid = threadIdx.x;
    int w = tid >> 6, lane = tid & 63, quad = lane >> 4, l16 = lane & 15;
    int wm = (w >> 1) * 64, wn = (w & 1) * 64;
    int x7 = l16 & 7;

    // staging source pointers (inverse-swizzled global, linear LDS dest)
    const u16* Aga[4]; const u16* Bga[2];
#pragma unroll
    for (int i = 0; i < 4; ++i) {
        int idx = i * 512 + tid, row = idx >> 3;
        int lu = (idx & 7) ^ (row & 7);
        Aga[i] = A + (size_t)(mb + row) * D_ + lu * 8;
    }
#pragma unroll
    for (int i = 0; i < 2; ++i) {
        int idx = i * 512 + tid, row = idx >> 3;
        int lu = (idx & 7) ^ (row & 7);
        Bga[i] = BT + (size_t)(nb + row) * D_ + lu * 8;
    }

    facc4 acc[4][4] = {};

    // prologue: stage K-tile 0 into buffer 0
#pragma unroll
    for (int i = 0; i < 4; ++i) gl_lds16(Aga[i], S + (i * 512 + tid) * 8);
#pragma unroll
    for (int i = 0; i < 2; ++i) gl_lds16(Bga[i], S + ABUF_ + (i * 512 + tid) * 8);
    asm volatile("s_waitcnt vmcnt(0)" ::: "memory");
    __builtin_amdgcn_sched_barrier(0);
    __builtin_amdgcn_s_barrier();
    __builtin_amdgcn_sched_barrier(0);

    for (int kt = 0; kt < 16; ++kt) {
        u16* Cb = S + (kt & 1) * TBUF_;           // current (staged, ready)
        u16* Nb = S + ((kt & 1) ^ 1) * TBUF_;     // next (fully consumed last iter)
        if (kt < 15) {                            // issue next-tile stage first
            int ko = (kt + 1) * 64;
#pragma unroll
            for (int i = 0; i < 4; ++i) gl_lds16(Aga[i] + ko, Nb + (i * 512 + tid) * 8);
#pragma unroll
            for (int i = 0; i < 2; ++i) gl_lds16(Bga[i] + ko, Nb + ABUF_ + (i * 512 + tid) * 8);
        }
#pragma unroll
        for (int k2 = 0; k2 < 2; ++k2) {
            int pu = ((k2 * 4 + quad) ^ x7) * 8;  // swizzled 16B-unit offset
            bfrag8 af[4], bf[4];
#pragma unroll
            for (int mt = 0; mt < 4; ++mt)
                af[mt] = *(const bfrag8*)(Cb + (wm + mt * 16 + l16) * 64 + pu);
#pragma unroll
            for (int nt = 0; nt < 4; ++nt)
                bf[nt] = *(const bfrag8*)(Cb + ABUF_ + (wn + nt * 16 + l16) * 64 + pu);
            __builtin_amdgcn_s_setprio(1);
#pragma unroll
            for (int mt = 0; mt < 4; ++mt)
#pragma unroll
                for (int nt = 0; nt < 4; ++nt)
                    acc[mt][nt] = __builtin_amdgcn_mfma_f32_16x16x32_bf16(af[mt], bf[nt], acc[mt][nt], 0, 0, 0);
            __builtin_amdgcn_s_setprio(0);
        }
        // single drain+barrier per K-tile: next tile is now fully landed
        asm volatile("s_waitcnt vmcnt(0)" ::: "memory");
        __builtin_amdgcn_sched_barrier(0);
        __builtin_amdgcn_s_barrier();
        __builtin_amdgcn_sched_barrier(0);
    }

#pragma unroll
    for (int mt = 0; mt < 4; ++mt) {
        int m_base = mb + wm + mt * 16 + quad * 4;
#pragma unroll
        for (int nt = 0; nt < 4; ++nt) {
            int n = nb + wn + nt * 16 + l16;
            float bv = bias[n];
            int h = n >> 6, dd = n & 63;
#pragma unroll
            for (int r = 0; r < 4; ++r) {
                int m = m_base + r;
                float v = (acc[mt][nt][r] + bv) * scale;
                int bi = m >> 11, s = m & (S_ - 1);
                if (mode == 0) {
                    ((u16*)Cout)[(((bi * H_ + h) * S_) + s) * DH_ + dd] = bfr(v);
                } else if (mode == 1) {
                    ((u16*)Cout)[(((bi * H_ + h) * DH_) + dd) * S_ + s] = bfr(v);
                } else {
                    ((float*)Cout)[(size_t)m * D_ + n] = v;
                }
            }
        }
    }
}

#define CE_Q 0.18033688011112042f   // log2(e)/sqrt(DH), folded into Q

// 1D grid (768): xcd = lid&7, s = lid>>3 in [0,96); z = s>>5 selects weight;
// inner = s&31: y = xcd*4 + (inner>>3) in [0,32), x = inner&7. Bijective.
__global__ __launch_bounds__(512, 2) void gemm_qkv(const u16* __restrict__ A,
                                                const u16* __restrict__ WTq, const float* __restrict__ bq, u16* __restrict__ Qb,
                                                const u16* __restrict__ WTk, const float* __restrict__ bk, u16* __restrict__ Kb,
                                                const u16* __restrict__ WTv, const float* __restrict__ bv, u16* __restrict__ VTb) {
    __shared__ __attribute__((aligned(16))) u16 Sh[2 * TBUF_];   // 96 KiB
    int lid = blockIdx.x;
    int xcd = lid & 7, s = lid >> 3;
    int z = s >> 5, inner = s & 31;
    int mb = (xcd * 4 + (inner >> 3)) * 256;
    int nb = (inner & 7) * 128;
    switch (z) {
        case 0: gemm_body256(A, WTq, bq, Qb, 0, CE_Q, Sh, nb, mb); break;   // Q pre-scaled
        case 1: gemm_body256(A, WTk, bk, Kb, 0, 1.0f, Sh, nb, mb); break;
        default: gemm_body256(A, WTv, bv, VTb, 1, 1.0f, Sh, nb, mb); break;
    }
}

__global__ __launch_bounds__(512, 2) void gemm_o(const u16* __restrict__ A,
                                              const u16* __restrict__ WTo, const float* __restrict__ bo,
                                              float* __restrict__ out) {
    __shared__ __attribute__((aligned(16))) u16 Sh[2 * TBUF_];   // 96 KiB
    int lid = blockIdx.x;
    int xcd = lid & 7, s = lid >> 3;           // s in [0,32)
    int mb = (xcd * 4 + (s >> 3)) * 256;
    int nb = (s & 7) * 128;
    gemm_body256(A, WTo, bo, out, 2, 1.0f, Sh, nb, mb);
}

// ---------------------------------------------------------------------------
// Flash attention, S^T/O^T formulation, fixed-base softmax.
// Block = 128 q-rows of one (b,h), 4 waves x 32 rows each; K/V tile (32 keys)
// staged once per block-iter into LDS (global_load_lds) and shared by all
// 4 waves. XOR swizzle via inverse-swizzled global source. LPT dispatch,
// bh-affinity XCD swizzle, pre-packed padding bitmask. (R2, verified)
// ---------------------------------------------------------------------------
// exp2 + pack + lane-transpose (bpermute) + PV accumulate for one q-tile
__device__ __forceinline__ void soft_pv(const float* p, float& lp, facc4* oaccq,
                                        const bfrag8* vf, int a0, int a1, bool qlo) {
    float rs = 0.f;
    unsigned pk[4];
#pragma unroll
    for (int j = 0; j < 4; ++j) {
        float e0 = exp2f(p[2 * j]);
        float e1 = exp2f(p[2 * j + 1]);
        rs += e0; rs += e1;
        pk[j] = __builtin_amdgcn_perm(__float_as_uint(e1), __float_as_uint(e0), 0x07060302u);
    }
    lp += rs;                                   // per-lane partial; reduced once per chunk
    union { unsigned d[4]; bfrag8 v; } pb;
    {
        unsigned lo, hi;
        lo = __builtin_amdgcn_ds_bpermute(a0, (int)pk[0]);
        hi = __builtin_amdgcn_ds_bpermute(a0, (int)pk[2]);
        pb.d[0] = qlo ? lo : hi;
        lo = __builtin_amdgcn_ds_bpermute(a0, (int)pk[1]);
        hi = __builtin_amdgcn_ds_bpermute(a0, (int)pk[3]);
        pb.d[1] = qlo ? lo : hi;
        lo = __builtin_amdgcn_ds_bpermute(a1, (int)pk[0]);
        hi = __builtin_amdgcn_ds_bpermute(a1, (int)pk[2]);
        pb.d[2] = qlo ? lo : hi;
        lo = __builtin_amdgcn_ds_bpermute(a1, (int)pk[1]);
        hi = __builtin_amdgcn_ds_bpermute(a1, (int)pk[3]);
        pb.d[3] = qlo ? lo : hi;
    }
    __builtin_amdgcn_s_setprio(1);
#pragma unroll
    for (int dt = 0; dt < 4; ++dt)
        oaccq[dt] = __builtin_amdgcn_mfma_f32_16x16x32_bf16(vf[dt], pb.v, oaccq[dt], 0, 0, 0);
    __builtin_amdgcn_s_setprio(0);
}

__global__ __launch_bounds__(256, 4) void attn(const u16* __restrict__ Q,
                                               const u16* __restrict__ K,
                                               const u16* __restrict__ VT,
                                               const unsigned* __restrict__ pmw,
                                               u16* __restrict__ Aout) {
    __shared__ __attribute__((aligned(16))) u16 Ks[32 * 64];   // [key][dh] 4KB
    __shared__ __attribute__((aligned(16))) u16 Vs[64 * 32];   // [d][key] 4KB

    int tid = threadIdx.x, w = tid >> 6, lane = tid & 63;
    int quad = lane >> 4, l16 = lane & 15;

    // lid -> (bh, ci): all 16 blocks of one bh share lid&7 (same XCD);
    // j = lid>>6 ascending => ci = 15-j descending (LPT: long blocks first).
    int lid = blockIdx.x;                       // [0,1024)
    int bh  = (lid & 7) * 8 + ((lid >> 3) & 7); // [0,64)
    int ci  = 15 - (lid >> 6);                  // [0,16) chunk of 128 q-rows
    int b = bh >> 4, h = bh & 15;

    int qbase = ci * 128;
    int qw = qbase + w * 32;                    // this wave's 32 q-rows
    int tmax = (qbase >> 5) + 3;                // tiles 0..tmax (32 keys each)

    const u16* Qp = Q + (size_t)(b * H_ + h) * S_ * DH_;
    const u16* Kp = K + (size_t)(b * H_ + h) * S_ * DH_;
    const u16* Vp = VT + (size_t)(b * H_ + h) * DH_ * S_;
    const unsigned* pmb = pmw + b * 64;
    u16* Ao = Aout + (size_t)b * S_ * D_ + h * DH_;

    // staging thread map (inverse-swizzled global source, linear LDS dest)
    int krow = tid >> 3, ku = tid & 7;          // K tile: 32 rows x 8x16B units
    const u16* Kg = Kp + krow * DH_ + ((ku ^ (krow & 7)) * 8);
    u16* Kl = Ks + tid * 8;
    int vrow = tid >> 2, vu = tid & 3;          // V tile: 64 rows x 4x16B units
    const u16* Vg = Vp + vrow * S_ + ((vu ^ (vrow & 3)) * 8);
    u16* Vl = Vs + tid * 8;

    // swizzled read constants
    int k7 = l16 & 7, v3 = l16 & 3;

    // bpermute byte-addresses for the P^T lane permute (loop-invariant)
    int a0 = ((((2 * quad) & 3) * 16 + l16) << 2);
    int a1 = ((((2 * quad + 1) & 3) * 16 + l16) << 2);
    bool qlo = quad < 2;

    bfrag8 qf[2][2];
#pragma unroll
    for (int qt = 0; qt < 2; ++qt)
#pragma unroll
        for (int cc = 0; cc < 2; ++cc)
            qf[qt][cc] = *(const bfrag8*)(Qp + (qw + qt * 16 + l16) * DH_ + cc * 32 + quad * 8);

    facc4 oacc[2][4] = {};                      // O^T: [qt][dt], row=d, col=q=l16
    float lp[2] = {0.f, 0.f};                   // per-lane partial denominators

    for (int t = 0; t <= tmax; ++t) {
        int k0 = t * 32;
        __syncthreads();                        // prior tile's readers done
        gl_lds16(Kg + k0 * DH_, Kl);
        gl_lds16(Vg + k0, Vl);
        __syncthreads();                        // staged data visible

        // K fragments from LDS (swizzled read; contents == R0's global frags)
        bfrag8 kf00 = *(const bfrag8*)(Ks + (l16 * 8        + ((quad)     ^ k7)) * 8);
        bfrag8 kf01 = *(const bfrag8*)(Ks + (l16 * 8        + ((quad + 4) ^ k7)) * 8);
        bfrag8 kf10 = *(const bfrag8*)(Ks + ((l16 + 16) * 8 + ((quad)     ^ k7)) * 8);
        bfrag8 kf11 = *(const bfrag8*)(Ks + ((l16 + 16) * 8 + ((quad + 4) ^ k7)) * 8);
        bfrag8 vf[4];
#pragma unroll
        for (int dt = 0; dt < 4; ++dt)
            vf[dt] = *(const bfrag8*)(Vs + ((dt * 16 + l16) * 4 + (quad ^ v3)) * 8);

        unsigned vm = pmb[t];

        facc4 st[2][2] = {};                    // S^T (pre-scaled): row=key, col=q
        __builtin_amdgcn_s_setprio(1);
#pragma unroll
        for (int qt = 0; qt < 2; ++qt) {
            st[qt][0] = __builtin_amdgcn_mfma_f32_16x16x32_bf16(kf00, qf[qt][0], st[qt][0], 0, 0, 0);
            st[qt][0] = __builtin_amdgcn_mfma_f32_16x16x32_bf16(kf01, qf[qt][1], st[qt][0], 0, 0, 0);
            st[qt][1] = __builtin_amdgcn_mfma_f32_16x16x32_bf16(kf10, qf[qt][0], st[qt][1], 0, 0, 0);
            st[qt][1] = __builtin_amdgcn_mfma_f32_16x16x32_bf16(kf11, qf[qt][1], st[qt][1], 0, 0, 0);
        }
        __builtin_amdgcn_s_setprio(0);

        if (vm == 0xffffffffu && k0 + 31 < qw) {
            // interior, fully valid: zero mask VALU
#pragma unroll
            for (int qt = 0; qt < 2; ++qt) {
                float p[8];
#pragma unroll
                for (int kt = 0; kt < 2; ++kt)
#pragma unroll
                    for (int r = 0; r < 4; ++r) p[kt * 4 + r] = st[qt][kt][r];
                soft_pv(p, lp[qt], oacc[qt], vf, a0, a1, qlo);
            }
        } else {
            // diagonal / padded / above-diagonal tile: per-element mask
#pragma unroll
            for (int qt = 0; qt < 2; ++qt) {
                int q0 = qw + qt * 16;
                float p[8];
#pragma unroll
                for (int kt = 0; kt < 2; ++kt)
#pragma unroll
                    for (int r = 0; r < 4; ++r) {
                        int kl = kt * 16 + quad * 4 + r;
                        bool ok = ((vm >> kl) & 1u) && (k0 + kl <= q0 + l16);
                        p[kt * 4 + r] = ok ? st[qt][kt][r] : -1e30f;
                    }
                soft_pv(p, lp[qt], oacc[qt], vf, a0, a1, qlo);
            }
        }
    }

    // finalize: reduce l across quads, normalize, store O^T
#pragma unroll
    for (int qt = 0; qt < 2; ++qt) {
        float l = lp[qt];
        l += __shfl_xor(l, 16);
        l += __shfl_xor(l, 32);
        float linv = (l > 0.f) ? 1.f / l : 0.f;
        size_t qoff = (size_t)(qw + qt * 16 + l16) * D_;
#pragma unroll
        for (int dt = 0; dt < 4; ++dt) {
            union { u16 hh[4]; u64 q; } pk4;
#pragma unroll
            for (int r = 0; r < 4; ++r) pk4.hh[r] = bfr(oacc[qt][dt][r] * linv);
            *(u64*)(Ao + qoff + dt * 16 + quad * 4) = pk4.q;
        }
    }
}

// ---------------------------------------------------------------------------
extern "C" void kernel_launch(void* const* d_in, const int* in_sizes, int n_in,
                              void* d_out, int out_size, void* d_ws, size_t ws_size,
                              hipStream_t stream) {
    const float* x  = (const float*)d_in[0];
    const float* Wq = (const float*)d_in[1];
    const float* bq = (const float*)d_in[2];
    const float* Wk = (const float*)d_in[3];
    const float* bk = (const float*)d_in[4];
    const float* Wv = (const float*)d_in[5];
    const float* bv = (const float*)d_in[6];
    const float* Wo = (const float*)d_in[7];
    const float* bo = (const float*)d_in[8];
    const int*   pm = (const int*)d_in[9];
    float* out = (float*)d_out;

    char* ws = (char*)d_ws;
    const size_t SZ_XD = (size_t)M_ * D_ * 2;   // 16 MiB bf16 [M,D]
    const size_t SZ_W  = (size_t)D_ * D_ * 2;   //  2 MiB bf16 [D,D]
    u16* X16 = (u16*)ws;                 // reused as attended output (safe: X16's
                                         // last read is the V GEMM; attn writes later)
    u16* WTq = (u16*)(ws + SZ_XD);
    u16* WTk = (u16*)(ws + SZ_XD + SZ_W);
    u16* WTv = (u16*)(ws + SZ_XD + 2 * SZ_W);
    u16* WTo = (u16*)(ws + SZ_XD + 3 * SZ_W);
    u16* Qb  = (u16*)(ws + SZ_XD + 4 * SZ_W);
    u16* Kb  = (u16*)(ws + 2 * SZ_XD + 4 * SZ_W);
    u16* VTb = (u16*)(ws + 3 * SZ_XD + 4 * SZ_W);
    u16* Att = X16;
    unsigned* PMW = (unsigned*)WTq;      // WTq dead after gemm_qkv; pack_pm runs after

    cvt_x<<<(M_ * D_) / (256 * 4), 256, 0, stream>>>(x, X16, M_ * D_);
    cvt_wt<<<dim3(D_ / 32, D_ / 32, 4), 256, 0, stream>>>(Wq, Wk, Wv, Wo, WTq, WTk, WTv, WTo);

    gemm_qkv<<<dim3(768), 512, 0, stream>>>(X16, WTq, bq, Qb, WTk, bk, Kb, WTv, bv, VTb);

    pack_pm<<<4, 64, 0, stream>>>(pm, PMW);

    attn<<<dim3(1024), 256, 0, stream>>>(Qb, Kb, VTb, PMW, Att);

    gemm_o<<<dim3(256), 512, 0, stream>>>(Att, WTo, bo, out);
}

// Round 6
// 268.194 us; speedup vs baseline: 1.7698x; 1.0414x over previous
//
#include <hip/hip_runtime.h>
#include <hip/hip_bf16.h>

#define B_   4
#define S_   2048
#define D_   1024
#define H_   16
#define DH_  64
#define M_   (B_ * S_)

typedef __attribute__((ext_vector_type(8))) short  bfrag8;   // 8 bf16 = 4 VGPRs
typedef __attribute__((ext_vector_type(4))) float  facc4;    // 4 fp32 accum
typedef unsigned short u16;
typedef unsigned long long u64;

__device__ __forceinline__ u16 f2bf(float f) {
    union { __hip_bfloat16 h; u16 u; } c;
    c.h = __float2bfloat16(f);
    return c.u;
}

// manual RNE fp32->bf16 (finite inputs only)
__device__ __forceinline__ u16 bfr(float f) {
    unsigned b = __float_as_uint(f);
    return (u16)((b + 0x7FFFu + ((b >> 16) & 1u)) >> 16);
}

// async global->LDS, 16B per lane; LDS dest must be wave-uniform base + lane*16
__device__ __forceinline__ void gl_lds16(const u16* g, u16* l) {
    __builtin_amdgcn_global_load_lds((const __attribute__((address_space(1))) void*)g,
                                     (__attribute__((address_space(3))) void*)l,
                                     16, 0, 0);
}

// ---------------------------------------------------------------------------
// fp32 -> bf16 elementwise convert (x)
// ---------------------------------------------------------------------------
__global__ __launch_bounds__(256) void cvt_x(const float* __restrict__ x,
                                             u16* __restrict__ o, int n) {
    int i = (blockIdx.x * 256 + threadIdx.x) * 4;
    if (i >= n) return;
    float4 v = *(const float4*)(x + i);
    ushort4 r;
    r.x = f2bf(v.x); r.y = f2bf(v.y); r.z = f2bf(v.z); r.w = f2bf(v.w);
    *(ushort4*)(o + i) = r;
}

// ---------------------------------------------------------------------------
// fp32 W[k][n] -> bf16 WT[n][k] transpose+convert, 32x32 LDS tiles.
// ---------------------------------------------------------------------------
__global__ __launch_bounds__(256) void cvt_wt(const float* __restrict__ w0, const float* __restrict__ w1,
                                              const float* __restrict__ w2, const float* __restrict__ w3,
                                              u16* __restrict__ o0, u16* __restrict__ o1,
                                              u16* __restrict__ o2, u16* __restrict__ o3) {
    const float* w; u16* o;
    switch (blockIdx.z) {
        case 0: w = w0; o = o0; break;
        case 1: w = w1; o = o1; break;
        case 2: w = w2; o = o2; break;
        default: w = w3; o = o3; break;
    }
    __shared__ u16 t[32][33];
    int kb = blockIdx.x * 32, nb = blockIdx.y * 32;
    int c = threadIdx.x & 31, r0 = threadIdx.x >> 5;
#pragma unroll
    for (int i = 0; i < 4; i++) {
        int r = r0 + 8 * i;
        t[r][c] = f2bf(w[(kb + r) * D_ + nb + c]);
    }
    __syncthreads();
#pragma unroll
    for (int i = 0; i < 4; i++) {
        int r = r0 + 8 * i;
        o[(nb + r) * D_ + kb + c] = t[c][r];
    }
}

// ---------------------------------------------------------------------------
// pack padding mask to bitmask words: pmw[b*64 + t] bit i <-> key t*32+i valid
// ---------------------------------------------------------------------------
__global__ __launch_bounds__(64) void pack_pm(const int* __restrict__ pm,
                                              unsigned* __restrict__ pmw) {
    int b = blockIdx.x, lane = threadIdx.x;
#pragma unroll
    for (int j = 0; j < 32; ++j) {
        u64 m = __ballot(pm[b * S_ + j * 64 + lane] != 0);
        if (lane == 0) {
            pmw[b * 64 + 2 * j]     = (unsigned)m;
            pmw[b * 64 + 2 * j + 1] = (unsigned)(m >> 32);
        }
    }
}

// ---------------------------------------------------------------------------
// R4 GEMM: C[M,N] = (A[M,K] @ BT[N,K]^T + bias) * scale.
// BM=256 x BN=128 x BK=64, 512 threads / 8 waves, double-buffered 96KB LDS,
// stage-before-compute, one vmcnt(0)+s_barrier per K-tile. T1 XCD
// panel-affinity swizzle (R4: FETCH-dup fix, verified). T2 swizzle, T5.
// ---------------------------------------------------------------------------
#define ABUF_ (256 * 64)            // u16 per A region
#define TBUF_ ((256 + 128) * 64)    // u16 per buffer (A + B)

__device__ __forceinline__ void gemm_body256(const u16* __restrict__ A,
                                             const u16* __restrict__ BT,
                                             const float* __restrict__ bias,
                                             void* __restrict__ Cout, int mode, float scale,
                                             u16* S, int nb, int mb) {
    int tid = threadIdx.x;
    int w = tid >> 6, lane = tid & 63, quad = lane >> 4, l16 = lane & 15;
    int wm = (w >> 1) * 64, wn = (w & 1) * 64;
    int x7 = l16 & 7;

    // staging source pointers (inverse-swizzled global, linear LDS dest)
    const u16* Aga[4]; const u16* Bga[2];
#pragma unroll
    for (int i = 0; i < 4; ++i) {
        int idx = i * 512 + tid, row = idx >> 3;
        int lu = (idx & 7) ^ (row & 7);
        Aga[i] = A + (size_t)(mb + row) * D_ + lu * 8;
    }
#pragma unroll
    for (int i = 0; i < 2; ++i) {
        int idx = i * 512 + tid, row = idx >> 3;
        int lu = (idx & 7) ^ (row & 7);
        Bga[i] = BT + (size_t)(nb + row) * D_ + lu * 8;
    }

    facc4 acc[4][4] = {};

    // prologue: stage K-tile 0 into buffer 0
#pragma unroll
    for (int i = 0; i < 4; ++i) gl_lds16(Aga[i], S + (i * 512 + tid) * 8);
#pragma unroll
    for (int i = 0; i < 2; ++i) gl_lds16(Bga[i], S + ABUF_ + (i * 512 + tid) * 8);
    asm volatile("s_waitcnt vmcnt(0)" ::: "memory");
    __builtin_amdgcn_sched_barrier(0);
    __builtin_amdgcn_s_barrier();
    __builtin_amdgcn_sched_barrier(0);

    for (int kt = 0; kt < 16; ++kt) {
        u16* Cb = S + (kt & 1) * TBUF_;           // current (staged, ready)
        u16* Nb = S + ((kt & 1) ^ 1) * TBUF_;     // next (fully consumed last iter)
        if (kt < 15) {                            // issue next-tile stage first
            int ko = (kt + 1) * 64;
#pragma unroll
            for (int i = 0; i < 4; ++i) gl_lds16(Aga[i] + ko, Nb + (i * 512 + tid) * 8);
#pragma unroll
            for (int i = 0; i < 2; ++i) gl_lds16(Bga[i] + ko, Nb + ABUF_ + (i * 512 + tid) * 8);
        }
#pragma unroll
        for (int k2 = 0; k2 < 2; ++k2) {
            int pu = ((k2 * 4 + quad) ^ x7) * 8;  // swizzled 16B-unit offset
            bfrag8 af[4], bf[4];
#pragma unroll
            for (int mt = 0; mt < 4; ++mt)
                af[mt] = *(const bfrag8*)(Cb + (wm + mt * 16 + l16) * 64 + pu);
#pragma unroll
            for (int nt = 0; nt < 4; ++nt)
                bf[nt] = *(const bfrag8*)(Cb + ABUF_ + (wn + nt * 16 + l16) * 64 + pu);
            __builtin_amdgcn_s_setprio(1);
#pragma unroll
            for (int mt = 0; mt < 4; ++mt)
#pragma unroll
                for (int nt = 0; nt < 4; ++nt)
                    acc[mt][nt] = __builtin_amdgcn_mfma_f32_16x16x32_bf16(af[mt], bf[nt], acc[mt][nt], 0, 0, 0);
            __builtin_amdgcn_s_setprio(0);
        }
        // single drain+barrier per K-tile: next tile is now fully landed
        asm volatile("s_waitcnt vmcnt(0)" ::: "memory");
        __builtin_amdgcn_sched_barrier(0);
        __builtin_amdgcn_s_barrier();
        __builtin_amdgcn_sched_barrier(0);
    }

#pragma unroll
    for (int mt = 0; mt < 4; ++mt) {
        int m_base = mb + wm + mt * 16 + quad * 4;
#pragma unroll
        for (int nt = 0; nt < 4; ++nt) {
            int n = nb + wn + nt * 16 + l16;
            float bv = bias[n];
            int h = n >> 6, dd = n & 63;
#pragma unroll
            for (int r = 0; r < 4; ++r) {
                int m = m_base + r;
                float v = (acc[mt][nt][r] + bv) * scale;
                int bi = m >> 11, s = m & (S_ - 1);
                if (mode == 0) {
                    ((u16*)Cout)[(((bi * H_ + h) * S_) + s) * DH_ + dd] = bfr(v);
                } else if (mode == 1) {
                    ((u16*)Cout)[(((bi * H_ + h) * DH_) + dd) * S_ + s] = bfr(v);
                } else {
                    ((float*)Cout)[(size_t)m * D_ + n] = v;
                }
            }
        }
    }
}

#define CE_Q 0.18033688011112042f   // log2(e)/sqrt(DH), folded into Q

// 1D grid (768): xcd = lid&7, s = lid>>3 in [0,96); z = s>>5 selects weight;
// inner = s&31: y = xcd*4 + (inner>>3) in [0,32), x = inner&7. Bijective.
__global__ __launch_bounds__(512, 2) void gemm_qkv(const u16* __restrict__ A,
                                                const u16* __restrict__ WTq, const float* __restrict__ bq, u16* __restrict__ Qb,
                                                const u16* __restrict__ WTk, const float* __restrict__ bk, u16* __restrict__ Kb,
                                                const u16* __restrict__ WTv, const float* __restrict__ bv, u16* __restrict__ VTb) {
    __shared__ __attribute__((aligned(16))) u16 Sh[2 * TBUF_];   // 96 KiB
    int lid = blockIdx.x;
    int xcd = lid & 7, s = lid >> 3;
    int z = s >> 5, inner = s & 31;
    int mb = (xcd * 4 + (inner >> 3)) * 256;
    int nb = (inner & 7) * 128;
    switch (z) {
        case 0: gemm_body256(A, WTq, bq, Qb, 0, CE_Q, Sh, nb, mb); break;   // Q pre-scaled
        case 1: gemm_body256(A, WTk, bk, Kb, 0, 1.0f, Sh, nb, mb); break;
        default: gemm_body256(A, WTv, bv, VTb, 1, 1.0f, Sh, nb, mb); break;
    }
}

__global__ __launch_bounds__(512, 2) void gemm_o(const u16* __restrict__ A,
                                              const u16* __restrict__ WTo, const float* __restrict__ bo,
                                              float* __restrict__ out) {
    __shared__ __attribute__((aligned(16))) u16 Sh[2 * TBUF_];   // 96 KiB
    int lid = blockIdx.x;
    int xcd = lid & 7, s = lid >> 3;           // s in [0,32)
    int mb = (xcd * 4 + (s >> 3)) * 256;
    int nb = (s & 7) * 128;
    gemm_body256(A, WTo, bo, out, 2, 1.0f, Sh, nb, mb);
}

// ---------------------------------------------------------------------------
// Flash attention, S^T/O^T formulation, fixed-base softmax.
// Block = 128 q-rows of one (b,h), 4 waves x 32 rows each; K/V tile (32 keys)
// staged into LDS and shared by all 4 waves.
// R5 (attn was latency-bound: 1515 cyc/wave-iter vs ~500 issue work; the
// single-buffer stage serialized ~500 cyc of load latency per tile):
//  - DOUBLE-BUFFERED staging (R3/R4-verified stage-ahead): issue tile t+1
//    into spare buffer BEFORE computing tile t; ONE __syncthreads per iter
//    (its vmcnt-drain lands after ~900 cyc of compute -> latency hidden).
//  - mask word prefetched alongside (no serial uniform load per iter).
//  - balanced ci remap: ci_map={15,14,13,12,0,1,2,3,11,10,9,8,4,5,6,7};
//    any stride-4 group-set sums to 30 -> each CU's 4 resident blocks carry
//    exactly the mean load (was 112..160 iters, 18% tail).
// Read addresses, soft_pv, masks, epilogue unchanged (R2-verified).
// ---------------------------------------------------------------------------
// exp2 + pack + lane-transpose (bpermute) + PV accumulate for one q-tile
__device__ __forceinline__ void soft_pv(const float* p, float& lp, facc4* oaccq,
                                        const bfrag8* vf, int a0, int a1, bool qlo) {
    float rs = 0.f;
    unsigned pk[4];
#pragma unroll
    for (int j = 0; j < 4; ++j) {
        float e0 = exp2f(p[2 * j]);
        float e1 = exp2f(p[2 * j + 1]);
        rs += e0; rs += e1;
        pk[j] = __builtin_amdgcn_perm(__float_as_uint(e1), __float_as_uint(e0), 0x07060302u);
    }
    lp += rs;                                   // per-lane partial; reduced once per chunk
    union { unsigned d[4]; bfrag8 v; } pb;
    {
        unsigned lo, hi;
        lo = __builtin_amdgcn_ds_bpermute(a0, (int)pk[0]);
        hi = __builtin_amdgcn_ds_bpermute(a0, (int)pk[2]);
        pb.d[0] = qlo ? lo : hi;
        lo = __builtin_amdgcn_ds_bpermute(a0, (int)pk[1]);
        hi = __builtin_amdgcn_ds_bpermute(a0, (int)pk[3]);
        pb.d[1] = qlo ? lo : hi;
        lo = __builtin_amdgcn_ds_bpermute(a1, (int)pk[0]);
        hi = __builtin_amdgcn_ds_bpermute(a1, (int)pk[2]);
        pb.d[2] = qlo ? lo : hi;
        lo = __builtin_amdgcn_ds_bpermute(a1, (int)pk[1]);
        hi = __builtin_amdgcn_ds_bpermute(a1, (int)pk[3]);
        pb.d[3] = qlo ? lo : hi;
    }
    __builtin_amdgcn_s_setprio(1);
#pragma unroll
    for (int dt = 0; dt < 4; ++dt)
        oaccq[dt] = __builtin_amdgcn_mfma_f32_16x16x32_bf16(vf[dt], pb.v, oaccq[dt], 0, 0, 0);
    __builtin_amdgcn_s_setprio(0);
}

__global__ __launch_bounds__(256, 4) void attn(const u16* __restrict__ Q,
                                               const u16* __restrict__ K,
                                               const u16* __restrict__ VT,
                                               const unsigned* __restrict__ pmw,
                                               u16* __restrict__ Aout) {
    __shared__ __attribute__((aligned(16))) u16 Ks[2][32 * 64];   // [key][dh] 4KB x2
    __shared__ __attribute__((aligned(16))) u16 Vs[2][64 * 32];   // [d][key] 4KB x2

    int tid = threadIdx.x, w = tid >> 6, lane = tid & 63;
    int quad = lane >> 4, l16 = lane & 15;

    // lid -> (bh, ci): all 16 blocks of one bh share lid&7 (same XCD L2).
    int lid = blockIdx.x;                       // [0,1024)
    int bh  = (lid & 7) * 8 + ((lid >> 3) & 7); // [0,64)
    int g   = lid >> 6;                         // [0,16) chunk group
    int gq = g >> 2, gr = g & 3;                // balanced ci remap (see header)
    int ci = (gq == 0) ? 15 - gr : (gq == 1) ? gr : (gq == 2) ? 11 - gr : 4 + gr;
    int b = bh >> 4, h = bh & 15;

    int qbase = ci * 128;
    int qw = qbase + w * 32;                    // this wave's 32 q-rows
    int tmax = (qbase >> 5) + 3;                // tiles 0..tmax (32 keys each)

    const u16* Qp = Q + (size_t)(b * H_ + h) * S_ * DH_;
    const u16* Kp = K + (size_t)(b * H_ + h) * S_ * DH_;
    const u16* Vp = VT + (size_t)(b * H_ + h) * DH_ * S_;
    const unsigned* pmb = pmw + b * 64;
    u16* Ao = Aout + (size_t)b * S_ * D_ + h * DH_;

    // staging thread map (inverse-swizzled global source, linear LDS dest)
    int krow = tid >> 3, ku = tid & 7;          // K tile: 32 rows x 8x16B units
    const u16* Kg = Kp + krow * DH_ + ((ku ^ (krow & 7)) * 8);
    int vrow = tid >> 2, vu = tid & 3;          // V tile: 64 rows x 4x16B units
    const u16* Vg = Vp + vrow * S_ + ((vu ^ (vrow & 3)) * 8);
    u16* Kl[2] = { &Ks[0][tid * 8], &Ks[1][tid * 8] };
    u16* Vl[2] = { &Vs[0][tid * 8], &Vs[1][tid * 8] };

    // swizzled read constants
    int k7 = l16 & 7, v3 = l16 & 3;

    // bpermute byte-addresses for the P^T lane permute (loop-invariant)
    int a0 = ((((2 * quad) & 3) * 16 + l16) << 2);
    int a1 = ((((2 * quad + 1) & 3) * 16 + l16) << 2);
    bool qlo = quad < 2;

    bfrag8 qf[2][2];
#pragma unroll
    for (int qt = 0; qt < 2; ++qt)
#pragma unroll
        for (int cc = 0; cc < 2; ++cc)
            qf[qt][cc] = *(const bfrag8*)(Qp + (qw + qt * 16 + l16) * DH_ + cc * 32 + quad * 8);

    facc4 oacc[2][4] = {};                      // O^T: [qt][dt], row=d, col=q=l16
    float lp[2] = {0.f, 0.f};                   // per-lane partial denominators

    // prologue: stage tile 0 into buffer 0; prefetch mask word 0
    gl_lds16(Kg, Kl[0]);
    gl_lds16(Vg, Vl[0]);
    unsigned vmn = pmb[0];
    __syncthreads();                            // drains vmcnt; tile 0 ready

    for (int t = 0; t <= tmax; ++t) {
        int cur = t & 1, nxt = cur ^ 1;
        unsigned vm = vmn;
        if (t < tmax) {                         // issue next-tile stage FIRST
            int k1 = (t + 1) * 32;
            gl_lds16(Kg + k1 * DH_, Kl[nxt]);
            gl_lds16(Vg + k1, Vl[nxt]);
            vmn = pmb[t + 1];
        }
        int k0 = t * 32;
        const u16* Kc = Ks[cur];
        const u16* Vc = Vs[cur];

        // K fragments from LDS (swizzled read; contents == R0's global frags)
        bfrag8 kf00 = *(const bfrag8*)(Kc + (l16 * 8        + ((quad)     ^ k7)) * 8);
        bfrag8 kf01 = *(const bfrag8*)(Kc + (l16 * 8        + ((quad + 4) ^ k7)) * 8);
        bfrag8 kf10 = *(const bfrag8*)(Kc + ((l16 + 16) * 8 + ((quad)     ^ k7)) * 8);
        bfrag8 kf11 = *(const bfrag8*)(Kc + ((l16 + 16) * 8 + ((quad + 4) ^ k7)) * 8);
        bfrag8 vf[4];
#pragma unroll
        for (int dt = 0; dt < 4; ++dt)
            vf[dt] = *(const bfrag8*)(Vc + ((dt * 16 + l16) * 4 + (quad ^ v3)) * 8);

        facc4 st[2][2] = {};                    // S^T (pre-scaled): row=key, col=q
        __builtin_amdgcn_s_setprio(1);
#pragma unroll
        for (int qt = 0; qt < 2; ++qt) {
            st[qt][0] = __builtin_amdgcn_mfma_f32_16x16x32_bf16(kf00, qf[qt][0], st[qt][0], 0, 0, 0);
            st[qt][0] = __builtin_amdgcn_mfma_f32_16x16x32_bf16(kf01, qf[qt][1], st[qt][0], 0, 0, 0);
            st[qt][1] = __builtin_amdgcn_mfma_f32_16x16x32_bf16(kf10, qf[qt][0], st[qt][1], 0, 0, 0);
            st[qt][1] = __builtin_amdgcn_mfma_f32_16x16x32_bf16(kf11, qf[qt][1], st[qt][1], 0, 0, 0);
        }
        __builtin_amdgcn_s_setprio(0);

        if (vm == 0xffffffffu && k0 + 31 < qw) {
            // interior, fully valid: zero mask VALU
#pragma unroll
            for (int qt = 0; qt < 2; ++qt) {
                float p[8];
#pragma unroll
                for (int kt = 0; kt < 2; ++kt)
#pragma unroll
                    for (int r = 0; r < 4; ++r) p[kt * 4 + r] = st[qt][kt][r];
                soft_pv(p, lp[qt], oacc[qt], vf, a0, a1, qlo);
            }
        } else {
            // diagonal / padded / above-diagonal tile: per-element mask
#pragma unroll
            for (int qt = 0; qt < 2; ++qt) {
                int q0 = qw + qt * 16;
                float p[8];
#pragma unroll
                for (int kt = 0; kt < 2; ++kt)
#pragma unroll
                    for (int r = 0; r < 4; ++r) {
                        int kl = kt * 16 + quad * 4 + r;
                        bool ok = ((vm >> kl) & 1u) && (k0 + kl <= q0 + l16);
                        p[kt * 4 + r] = ok ? st[qt][kt][r] : -1e30f;
                    }
                soft_pv(p, lp[qt], oacc[qt], vf, a0, a1, qlo);
            }
        }
        __syncthreads();                        // next tile landed; cur free
    }

    // finalize: reduce l across quads, normalize, store O^T
#pragma unroll
    for (int qt = 0; qt < 2; ++qt) {
        float l = lp[qt];
        l += __shfl_xor(l, 16);
        l += __shfl_xor(l, 32);
        float linv = (l > 0.f) ? 1.f / l : 0.f;
        size_t qoff = (size_t)(qw + qt * 16 + l16) * D_;
#pragma unroll
        for (int dt = 0; dt < 4; ++dt) {
            union { u16 hh[4]; u64 q; } pk4;
#pragma unroll
            for (int r = 0; r < 4; ++r) pk4.hh[r] = bfr(oacc[qt][dt][r] * linv);
            *(u64*)(Ao + qoff + dt * 16 + quad * 4) = pk4.q;
        }
    }
}

// ---------------------------------------------------------------------------
extern "C" void kernel_launch(void* const* d_in, const int* in_sizes, int n_in,
                              void* d_out, int out_size, void* d_ws, size_t ws_size,
                              hipStream_t stream) {
    const float* x  = (const float*)d_in[0];
    const float* Wq = (const float*)d_in[1];
    const float* bq = (const float*)d_in[2];
    const float* Wk = (const float*)d_in[3];
    const float* bk = (const float*)d_in[4];
    const float* Wv = (const float*)d_in[5];
    const float* bv = (const float*)d_in[6];
    const float* Wo = (const float*)d_in[7];
    const float* bo = (const float*)d_in[8];
    const int*   pm = (const int*)d_in[9];
    float* out = (float*)d_out;

    char* ws = (char*)d_ws;
    const size_t SZ_XD = (size_t)M_ * D_ * 2;   // 16 MiB bf16 [M,D]
    const size_t SZ_W  = (size_t)D_ * D_ * 2;   //  2 MiB bf16 [D,D]
    u16* X16 = (u16*)ws;                 // reused as attended output (safe: X16's
                                         // last read is the V GEMM; attn writes later)
    u16* WTq = (u16*)(ws + SZ_XD);
    u16* WTk = (u16*)(ws + SZ_XD + SZ_W);
    u16* WTv = (u16*)(ws + SZ_XD + 2 * SZ_W);
    u16* WTo = (u16*)(ws + SZ_XD + 3 * SZ_W);
    u16* Qb  = (u16*)(ws + SZ_XD + 4 * SZ_W);
    u16* Kb  = (u16*)(ws + 2 * SZ_XD + 4 * SZ_W);
    u16* VTb = (u16*)(ws + 3 * SZ_XD + 4 * SZ_W);
    u16* Att = X16;
    unsigned* PMW = (unsigned*)WTq;      // WTq dead after gemm_qkv; pack_pm runs after

    cvt_x<<<(M_ * D_) / (256 * 4), 256, 0, stream>>>(x, X16, M_ * D_);
    cvt_wt<<<dim3(D_ / 32, D_ / 32, 4), 256, 0, stream>>>(Wq, Wk, Wv, Wo, WTq, WTk, WTv, WTo);

    gemm_qkv<<<dim3(768), 512, 0, stream>>>(X16, WTq, bq, Qb, WTk, bk, Kb, WTv, bv, VTb);

    pack_pm<<<4, 64, 0, stream>>>(pm, PMW);

    attn<<<dim3(1024), 256, 0, stream>>>(Qb, Kb, VTb, PMW, Att);

    gemm_o<<<dim3(256), 512, 0, stream>>>(Att, WTo, bo, out);
}

// Round 7
// 251.055 us; speedup vs baseline: 1.8907x; 1.0683x over previous
//
#include <hip/hip_runtime.h>
#include <hip/hip_bf16.h>

#define B_   4
#define S_   2048
#define D_   1024
#define H_   16
#define DH_  64
#define M_   (B_ * S_)

typedef __attribute__((ext_vector_type(8))) short  bfrag8;   // 8 bf16 = 4 VGPRs
typedef __attribute__((ext_vector_type(4))) float  facc4;    // 4 fp32 accum
typedef unsigned short u16;
typedef unsigned long long u64;

__device__ __forceinline__ u16 f2bf(float f) {
    union { __hip_bfloat16 h; u16 u; } c;
    c.h = __float2bfloat16(f);
    return c.u;
}

// manual RNE fp32->bf16 (finite inputs only)
__device__ __forceinline__ u16 bfr(float f) {
    unsigned b = __float_as_uint(f);
    return (u16)((b + 0x7FFFu + ((b >> 16) & 1u)) >> 16);
}

// async global->LDS, 16B per lane; LDS dest must be wave-uniform base + lane*16
__device__ __forceinline__ void gl_lds16(const u16* g, u16* l) {
    __builtin_amdgcn_global_load_lds((const __attribute__((address_space(1))) void*)g,
                                     (__attribute__((address_space(3))) void*)l,
                                     16, 0, 0);
}

// ---------------------------------------------------------------------------
// prep: fused input conversion (R6: was cvt_x + cvt_wt, 2 launches -> 1).
// bid < 4096:  fp32 x -> bf16 X16, 8 elems/thread.
// bid >= 4096: fp32 W[k][n] -> bf16 WT[n][k], 32x32 LDS transpose tiles.
// ---------------------------------------------------------------------------
__global__ __launch_bounds__(256) void prep(const float* __restrict__ x, u16* __restrict__ X16,
                                            const float* __restrict__ w0, const float* __restrict__ w1,
                                            const float* __restrict__ w2, const float* __restrict__ w3,
                                            u16* __restrict__ o0, u16* __restrict__ o1,
                                            u16* __restrict__ o2, u16* __restrict__ o3) {
    __shared__ u16 t[32][33];
    int bid = blockIdx.x;
    if (bid < 4096) {
        int i = (bid * 256 + threadIdx.x) * 8;
        float4 v0 = *(const float4*)(x + i);
        float4 v1 = *(const float4*)(x + i + 4);
        ushort4 r0, r1;
        r0.x = f2bf(v0.x); r0.y = f2bf(v0.y); r0.z = f2bf(v0.z); r0.w = f2bf(v0.w);
        r1.x = f2bf(v1.x); r1.y = f2bf(v1.y); r1.z = f2bf(v1.z); r1.w = f2bf(v1.w);
        *(ushort4*)(X16 + i) = r0;
        *(ushort4*)(X16 + i + 4) = r1;
    } else {
        int lid = bid - 4096;
        int z = lid >> 10, r = lid & 1023;
        const float* w; u16* o;
        switch (z) {
            case 0: w = w0; o = o0; break;
            case 1: w = w1; o = o1; break;
            case 2: w = w2; o = o2; break;
            default: w = w3; o = o3; break;
        }
        int kb = (r >> 5) * 32, nb = (r & 31) * 32;
        int c = threadIdx.x & 31, r0 = threadIdx.x >> 5;
#pragma unroll
        for (int i = 0; i < 4; i++) {
            int rr = r0 + 8 * i;
            t[rr][c] = f2bf(w[(kb + rr) * D_ + nb + c]);
        }
        __syncthreads();
#pragma unroll
        for (int i = 0; i < 4; i++) {
            int rr = r0 + 8 * i;
            o[(nb + rr) * D_ + kb + c] = t[c][rr];
        }
    }
}

// ---------------------------------------------------------------------------
// R6 GEMM: C[M,N] = (A[M,K] @ BT[N,K]^T + bias) * scale.
// BM=256 x BN=128 x BK=64, 512 threads / 8 waves. R6: T3+T4 proper --
// TRIPLE-buffered LDS (144KB), 2-tiles-ahead prefetch, counted vmcnt(6)
// (never drains to 0 in the main loop; m218: the isolated +38-73% lever),
// ONE raw s_barrier per K-tile, stage issued AFTER the barrier.
// Safety: passing barrier#k => all waves completed compute(k-1), so
// stage(k+2) overwriting buffer (k-1)%3 is race-free; own vmcnt(6)
// (= the 6 stage(k+1) loads in flight) + barrier => stage(k) landed for
// all waves before compute(k). Tail iterations use vmcnt(0)/no-issue.
// T1 XCD panel-affinity (R4-verified: FETCH 200->50MB). T2 swizzle
// (conflict-free, verified 0). T5 setprio. K-order identical (bitexact).
// ---------------------------------------------------------------------------
#define ABUF_ (256 * 64)            // u16 per A region
#define TBUF_ ((256 + 128) * 64)    // u16 per buffer (A + B)
#define NKT_  16                    // D_/64 K-tiles

__device__ __forceinline__ void gemm_body256(const u16* __restrict__ A,
                                             const u16* __restrict__ BT,
                                             const float* __restrict__ bias,
                                             void* __restrict__ Cout, int mode, float scale,
                                             u16* S, int nb, int mb) {
    int tid = threadIdx.x;
    int w = tid >> 6, lane = tid & 63, quad = lane >> 4, l16 = lane & 15;
    int wm = (w >> 1) * 64, wn = (w & 1) * 64;
    int x7 = l16 & 7;

    // staging source pointers (inverse-swizzled global, linear LDS dest)
    const u16* Aga[4]; const u16* Bga[2];
#pragma unroll
    for (int i = 0; i < 4; ++i) {
        int idx = i * 512 + tid, row = idx >> 3;
        int lu = (idx & 7) ^ (row & 7);
        Aga[i] = A + (size_t)(mb + row) * D_ + lu * 8;
    }
#pragma unroll
    for (int i = 0; i < 2; ++i) {
        int idx = i * 512 + tid, row = idx >> 3;
        int lu = (idx & 7) ^ (row & 7);
        Bga[i] = BT + (size_t)(nb + row) * D_ + lu * 8;
    }

    facc4 acc[4][4] = {};

    u16* Bu0 = S;
    u16* Bu1 = S + TBUF_;
    u16* Bu2 = S + 2 * TBUF_;

    auto stage = [&](u16* Nb, int ko) {
#pragma unroll
        for (int i = 0; i < 4; ++i) gl_lds16(Aga[i] + ko, Nb + (i * 512 + tid) * 8);
#pragma unroll
        for (int i = 0; i < 2; ++i) gl_lds16(Bga[i] + ko, Nb + ABUF_ + (i * 512 + tid) * 8);
    };
    auto compute = [&](const u16* Cb) {
#pragma unroll
        for (int k2 = 0; k2 < 2; ++k2) {
            int pu = ((k2 * 4 + quad) ^ x7) * 8;  // swizzled 16B-unit offset
            bfrag8 af[4], bf[4];
#pragma unroll
            for (int mt = 0; mt < 4; ++mt)
                af[mt] = *(const bfrag8*)(Cb + (wm + mt * 16 + l16) * 64 + pu);
#pragma unroll
            for (int nt = 0; nt < 4; ++nt)
                bf[nt] = *(const bfrag8*)(Cb + ABUF_ + (wn + nt * 16 + l16) * 64 + pu);
            __builtin_amdgcn_s_setprio(1);
#pragma unroll
            for (int mt = 0; mt < 4; ++mt)
#pragma unroll
                for (int nt = 0; nt < 4; ++nt)
                    acc[mt][nt] = __builtin_amdgcn_mfma_f32_16x16x32_bf16(af[mt], bf[nt], acc[mt][nt], 0, 0, 0);
            __builtin_amdgcn_s_setprio(0);
        }
    };

    // prologue: stage tiles 0,1 (12 loads in flight per wave)
    stage(Bu0, 0);
    stage(Bu1, 64);

    u16 *bc = Bu0, *bn = Bu1, *bs = Bu2;
    for (int kt = 0; kt < NKT_; ++kt) {
        // counted wait: vmcnt(6) leaves stage(kt+1)'s 6 loads in flight but
        // guarantees stage(kt) landed (FIFO retirement). Never 0 mid-loop.
        if (kt < NKT_ - 1) asm volatile("s_waitcnt vmcnt(6)" ::: "memory");
        else               asm volatile("s_waitcnt vmcnt(0)" ::: "memory");
        __builtin_amdgcn_sched_barrier(0);
        __builtin_amdgcn_s_barrier();
        __builtin_amdgcn_sched_barrier(0);
        if (kt + 2 < NKT_) stage(bs, (kt + 2) * 64);
        compute(bc);
        u16* tmp = bc; bc = bn; bn = bs; bs = tmp;
    }

#pragma unroll
    for (int mt = 0; mt < 4; ++mt) {
        int m_base = mb + wm + mt * 16 + quad * 4;
#pragma unroll
        for (int nt = 0; nt < 4; ++nt) {
            int n = nb + wn + nt * 16 + l16;
            float bv = bias[n];
            int h = n >> 6, dd = n & 63;
#pragma unroll
            for (int r = 0; r < 4; ++r) {
                int m = m_base + r;
                float v = (acc[mt][nt][r] + bv) * scale;
                int bi = m >> 11, s = m & (S_ - 1);
                if (mode == 0) {
                    ((u16*)Cout)[(((bi * H_ + h) * S_) + s) * DH_ + dd] = bfr(v);
                } else if (mode == 1) {
                    ((u16*)Cout)[(((bi * H_ + h) * DH_) + dd) * S_ + s] = bfr(v);
                } else {
                    ((float*)Cout)[(size_t)m * D_ + n] = v;
                }
            }
        }
    }
}

#define CE_Q 0.18033688011112042f   // log2(e)/sqrt(DH), folded into Q

// 1D grid (768): xcd = lid&7, s = lid>>3 in [0,96); z = s>>5 selects weight;
// inner = s&31: y = xcd*4 + (inner>>3) in [0,32), x = inner&7. Bijective.
__global__ __launch_bounds__(512, 1) void gemm_qkv(const u16* __restrict__ A,
                                                const u16* __restrict__ WTq, const float* __restrict__ bq, u16* __restrict__ Qb,
                                                const u16* __restrict__ WTk, const float* __restrict__ bk, u16* __restrict__ Kb,
                                                const u16* __restrict__ WTv, const float* __restrict__ bv, u16* __restrict__ VTb) {
    __shared__ __attribute__((aligned(16))) u16 Sh[3 * TBUF_];   // 144 KiB
    int lid = blockIdx.x;
    int xcd = lid & 7, s = lid >> 3;
    int z = s >> 5, inner = s & 31;
    int mb = (xcd * 4 + (inner >> 3)) * 256;
    int nb = (inner & 7) * 128;
    switch (z) {
        case 0: gemm_body256(A, WTq, bq, Qb, 0, CE_Q, Sh, nb, mb); break;   // Q pre-scaled
        case 1: gemm_body256(A, WTk, bk, Kb, 0, 1.0f, Sh, nb, mb); break;
        default: gemm_body256(A, WTv, bv, VTb, 1, 1.0f, Sh, nb, mb); break;
    }
}

__global__ __launch_bounds__(512, 1) void gemm_o(const u16* __restrict__ A,
                                              const u16* __restrict__ WTo, const float* __restrict__ bo,
                                              float* __restrict__ out) {
    __shared__ __attribute__((aligned(16))) u16 Sh[3 * TBUF_];   // 144 KiB
    int lid = blockIdx.x;
    int xcd = lid & 7, s = lid >> 3;           // s in [0,32)
    int mb = (xcd * 4 + (s >> 3)) * 256;
    int nb = (s & 7) * 128;
    gemm_body256(A, WTo, bo, out, 2, 1.0f, Sh, nb, mb);
}

// ---------------------------------------------------------------------------
// Flash attention, S^T/O^T formulation, fixed-base softmax.
// Block = 128 q-rows of one (b,h), 4 waves x 32 rows each; double-buffered
// K/V LDS staging (R5: stage-ahead, 1 barrier/iter), balanced ci remap,
// bh-affinity XCD swizzle. R6: padding bitmask built in-kernel (LDS pms[64]
// via per-wave ballots in the prologue) -- removes the pack_pm launch.
// ---------------------------------------------------------------------------
// exp2 + pack + lane-transpose (bpermute) + PV accumulate for one q-tile
__device__ __forceinline__ void soft_pv(const float* p, float& lp, facc4* oaccq,
                                        const bfrag8* vf, int a0, int a1, bool qlo) {
    float rs = 0.f;
    unsigned pk[4];
#pragma unroll
    for (int j = 0; j < 4; ++j) {
        float e0 = exp2f(p[2 * j]);
        float e1 = exp2f(p[2 * j + 1]);
        rs += e0; rs += e1;
        pk[j] = __builtin_amdgcn_perm(__float_as_uint(e1), __float_as_uint(e0), 0x07060302u);
    }
    lp += rs;                                   // per-lane partial; reduced once per chunk
    union { unsigned d[4]; bfrag8 v; } pb;
    {
        unsigned lo, hi;
        lo = __builtin_amdgcn_ds_bpermute(a0, (int)pk[0]);
        hi = __builtin_amdgcn_ds_bpermute(a0, (int)pk[2]);
        pb.d[0] = qlo ? lo : hi;
        lo = __builtin_amdgcn_ds_bpermute(a0, (int)pk[1]);
        hi = __builtin_amdgcn_ds_bpermute(a0, (int)pk[3]);
        pb.d[1] = qlo ? lo : hi;
        lo = __builtin_amdgcn_ds_bpermute(a1, (int)pk[0]);
        hi = __builtin_amdgcn_ds_bpermute(a1, (int)pk[2]);
        pb.d[2] = qlo ? lo : hi;
        lo = __builtin_amdgcn_ds_bpermute(a1, (int)pk[1]);
        hi = __builtin_amdgcn_ds_bpermute(a1, (int)pk[3]);
        pb.d[3] = qlo ? lo : hi;
    }
    __builtin_amdgcn_s_setprio(1);
#pragma unroll
    for (int dt = 0; dt < 4; ++dt)
        oaccq[dt] = __builtin_amdgcn_mfma_f32_16x16x32_bf16(vf[dt], pb.v, oaccq[dt], 0, 0, 0);
    __builtin_amdgcn_s_setprio(0);
}

__global__ __launch_bounds__(256, 4) void attn(const u16* __restrict__ Q,
                                               const u16* __restrict__ K,
                                               const u16* __restrict__ VT,
                                               const int* __restrict__ pm,
                                               u16* __restrict__ Aout) {
    __shared__ __attribute__((aligned(16))) u16 Ks[2][32 * 64];   // [key][dh] 4KB x2
    __shared__ __attribute__((aligned(16))) u16 Vs[2][64 * 32];   // [d][key] 4KB x2
    __shared__ unsigned pms[64];                                  // packed pad mask

    int tid = threadIdx.x, w = tid >> 6, lane = tid & 63;
    int quad = lane >> 4, l16 = lane & 15;

    // lid -> (bh, ci): all 16 blocks of one bh share lid&7 (same XCD L2).
    int lid = blockIdx.x;                       // [0,1024)
    int bh  = (lid & 7) * 8 + ((lid >> 3) & 7); // [0,64)
    int g   = lid >> 6;                         // [0,16) chunk group
    int gq = g >> 2, gr = g & 3;                // balanced ci remap
    int ci = (gq == 0) ? 15 - gr : (gq == 1) ? gr : (gq == 2) ? 11 - gr : 4 + gr;
    int b = bh >> 4, h = bh & 15;

    int qbase = ci * 128;
    int qw = qbase + w * 32;                    // this wave's 32 q-rows
    int tmax = (qbase >> 5) + 3;                // tiles 0..tmax (32 keys each)

    const u16* Qp = Q + (size_t)(b * H_ + h) * S_ * DH_;
    const u16* Kp = K + (size_t)(b * H_ + h) * S_ * DH_;
    const u16* Vp = VT + (size_t)(b * H_ + h) * DH_ * S_;
    u16* Ao = Aout + (size_t)b * S_ * D_ + h * DH_;

    // build padding bitmask: wave w covers words w*16..w*16+15 (2 per ballot)
#pragma unroll
    for (int i = 0; i < 8; ++i) {
        int j2 = w * 16 + i * 2;
        u64 m = __ballot(pm[b * S_ + j2 * 32 + lane] != 0);
        if (lane == 0) { pms[j2] = (unsigned)m; pms[j2 + 1] = (unsigned)(m >> 32); }
    }

    // staging thread map (inverse-swizzled global source, linear LDS dest)
    int krow = tid >> 3, ku = tid & 7;          // K tile: 32 rows x 8x16B units
    const u16* Kg = Kp + krow * DH_ + ((ku ^ (krow & 7)) * 8);
    int vrow = tid >> 2, vu = tid & 3;          // V tile: 64 rows x 4x16B units
    const u16* Vg = Vp + vrow * S_ + ((vu ^ (vrow & 3)) * 8);
    u16* Kl[2] = { &Ks[0][tid * 8], &Ks[1][tid * 8] };
    u16* Vl[2] = { &Vs[0][tid * 8], &Vs[1][tid * 8] };

    // swizzled read constants
    int k7 = l16 & 7, v3 = l16 & 3;

    // bpermute byte-addresses for the P^T lane permute (loop-invariant)
    int a0 = ((((2 * quad) & 3) * 16 + l16) << 2);
    int a1 = ((((2 * quad + 1) & 3) * 16 + l16) << 2);
    bool qlo = quad < 2;

    bfrag8 qf[2][2];
#pragma unroll
    for (int qt = 0; qt < 2; ++qt)
#pragma unroll
        for (int cc = 0; cc < 2; ++cc)
            qf[qt][cc] = *(const bfrag8*)(Qp + (qw + qt * 16 + l16) * DH_ + cc * 32 + quad * 8);

    facc4 oacc[2][4] = {};                      // O^T: [qt][dt], row=d, col=q=l16
    float lp[2] = {0.f, 0.f};                   // per-lane partial denominators

    // prologue: stage tile 0 into buffer 0
    gl_lds16(Kg, Kl[0]);
    gl_lds16(Vg, Vl[0]);
    __syncthreads();                            // drains vmcnt+lgkm; tile 0 + pms ready
    unsigned vmn = pms[0];

    for (int t = 0; t <= tmax; ++t) {
        int cur = t & 1, nxt = cur ^ 1;
        unsigned vm = vmn;
        if (t < tmax) {                         // issue next-tile stage FIRST
            int k1 = (t + 1) * 32;
            gl_lds16(Kg + k1 * DH_, Kl[nxt]);
            gl_lds16(Vg + k1, Vl[nxt]);
            vmn = pms[t + 1];
        }
        int k0 = t * 32;
        const u16* Kc = Ks[cur];
        const u16* Vc = Vs[cur];

        // K fragments from LDS (swizzled read; contents == R0's global frags)
        bfrag8 kf00 = *(const bfrag8*)(Kc + (l16 * 8        + ((quad)     ^ k7)) * 8);
        bfrag8 kf01 = *(const bfrag8*)(Kc + (l16 * 8        + ((quad + 4) ^ k7)) * 8);
        bfrag8 kf10 = *(const bfrag8*)(Kc + ((l16 + 16) * 8 + ((quad)     ^ k7)) * 8);
        bfrag8 kf11 = *(const bfrag8*)(Kc + ((l16 + 16) * 8 + ((quad + 4) ^ k7)) * 8);
        bfrag8 vf[4];
#pragma unroll
        for (int dt = 0; dt < 4; ++dt)
            vf[dt] = *(const bfrag8*)(Vc + ((dt * 16 + l16) * 4 + (quad ^ v3)) * 8);

        facc4 st[2][2] = {};                    // S^T (pre-scaled): row=key, col=q
        __builtin_amdgcn_s_setprio(1);
#pragma unroll
        for (int qt = 0; qt < 2; ++qt) {
            st[qt][0] = __builtin_amdgcn_mfma_f32_16x16x32_bf16(kf00, qf[qt][0], st[qt][0], 0, 0, 0);
            st[qt][0] = __builtin_amdgcn_mfma_f32_16x16x32_bf16(kf01, qf[qt][1], st[qt][0], 0, 0, 0);
            st[qt][1] = __builtin_amdgcn_mfma_f32_16x16x32_bf16(kf10, qf[qt][0], st[qt][1], 0, 0, 0);
            st[qt][1] = __builtin_amdgcn_mfma_f32_16x16x32_bf16(kf11, qf[qt][1], st[qt][1], 0, 0, 0);
        }
        __builtin_amdgcn_s_setprio(0);

        if (vm == 0xffffffffu && k0 + 31 < qw) {
            // interior, fully valid: zero mask VALU
#pragma unroll
            for (int qt = 0; qt < 2; ++qt) {
                float p[8];
#pragma unroll
                for (int kt = 0; kt < 2; ++kt)
#pragma unroll
                    for (int r = 0; r < 4; ++r) p[kt * 4 + r] = st[qt][kt][r];
                soft_pv(p, lp[qt], oacc[qt], vf, a0, a1, qlo);
            }
        } else {
            // diagonal / padded / above-diagonal tile: per-element mask
#pragma unroll
            for (int qt = 0; qt < 2; ++qt) {
                int q0 = qw + qt * 16;
                float p[8];
#pragma unroll
                for (int kt = 0; kt < 2; ++kt)
#pragma unroll
                    for (int r = 0; r < 4; ++r) {
                        int kl = kt * 16 + quad * 4 + r;
                        bool ok = ((vm >> kl) & 1u) && (k0 + kl <= q0 + l16);
                        p[kt * 4 + r] = ok ? st[qt][kt][r] : -1e30f;
                    }
                soft_pv(p, lp[qt], oacc[qt], vf, a0, a1, qlo);
            }
        }
        __syncthreads();                        // next tile landed; cur free
    }

    // finalize: reduce l across quads, normalize, store O^T
#pragma unroll
    for (int qt = 0; qt < 2; ++qt) {
        float l = lp[qt];
        l += __shfl_xor(l, 16);
        l += __shfl_xor(l, 32);
        float linv = (l > 0.f) ? 1.f / l : 0.f;
        size_t qoff = (size_t)(qw + qt * 16 + l16) * D_;
#pragma unroll
        for (int dt = 0; dt < 4; ++dt) {
            union { u16 hh[4]; u64 q; } pk4;
#pragma unroll
            for (int r = 0; r < 4; ++r) pk4.hh[r] = bfr(oacc[qt][dt][r] * linv);
            *(u64*)(Ao + qoff + dt * 16 + quad * 4) = pk4.q;
        }
    }
}

// ---------------------------------------------------------------------------
extern "C" void kernel_launch(void* const* d_in, const int* in_sizes, int n_in,
                              void* d_out, int out_size, void* d_ws, size_t ws_size,
                              hipStream_t stream) {
    const float* x  = (const float*)d_in[0];
    const float* Wq = (const float*)d_in[1];
    const float* bq = (const float*)d_in[2];
    const float* Wk = (const float*)d_in[3];
    const float* bk = (const float*)d_in[4];
    const float* Wv = (const float*)d_in[5];
    const float* bv = (const float*)d_in[6];
    const float* Wo = (const float*)d_in[7];
    const float* bo = (const float*)d_in[8];
    const int*   pm = (const int*)d_in[9];
    float* out = (float*)d_out;

    char* ws = (char*)d_ws;
    const size_t SZ_XD = (size_t)M_ * D_ * 2;   // 16 MiB bf16 [M,D]
    const size_t SZ_W  = (size_t)D_ * D_ * 2;   //  2 MiB bf16 [D,D]
    u16* X16 = (u16*)ws;                 // reused as attended output (safe: X16's
                                         // last read is the V GEMM; attn writes later)
    u16* WTq = (u16*)(ws + SZ_XD);
    u16* WTk = (u16*)(ws + SZ_XD + SZ_W);
    u16* WTv = (u16*)(ws + SZ_XD + 2 * SZ_W);
    u16* WTo = (u16*)(ws + SZ_XD + 3 * SZ_W);
    u16* Qb  = (u16*)(ws + SZ_XD + 4 * SZ_W);
    u16* Kb  = (u16*)(ws + 2 * SZ_XD + 4 * SZ_W);
    u16* VTb = (u16*)(ws + 3 * SZ_XD + 4 * SZ_W);
    u16* Att = X16;

    prep<<<dim3(8192), 256, 0, stream>>>(x, X16, Wq, Wk, Wv, Wo, WTq, WTk, WTv, WTo);

    gemm_qkv<<<dim3(768), 512, 0, stream>>>(X16, WTq, bq, Qb, WTk, bk, Kb, WTv, bv, VTb);

    attn<<<dim3(1024), 256, 0, stream>>>(Qb, Kb, VTb, pm, Att);

    gemm_o<<<dim3(256), 512, 0, stream>>>(Att, WTo, bo, out);
}